// Round 6
// baseline (7138.297 us; speedup 1.0000x reference)
//
#include <hip/hip_runtime.h>
#include <hip/hip_bf16.h>

typedef float f32x4 __attribute__((ext_vector_type(4)));
typedef short s16x8 __attribute__((ext_vector_type(8)));
typedef float floatx4 __attribute__((ext_vector_type(4)));

#define DEV static __device__ __forceinline__
#define WAITVM(N) asm volatile("s_waitcnt vmcnt(" #N ")" ::: "memory")

DEV void barrier_pipe() {
  __builtin_amdgcn_sched_barrier(0);
  __builtin_amdgcn_s_barrier();
  __builtin_amdgcn_sched_barrier(0);
}

DEV void gld_lds16(const void* g, void* l) {
  __builtin_amdgcn_global_load_lds(
      (const __attribute__((address_space(1))) void*)g,
      (__attribute__((address_space(3))) void*)l, 16, 0, 0);
}

DEV short f2bf(float x) {
  union { __hip_bfloat16 h; short s; } u;
  u.h = __float2bfloat16(x);
  return u.s;
}

DEV float bf2f(short s) {
  union { unsigned u; float f; } v;
  v.u = ((unsigned)(unsigned short)s) << 16;
  return v.f;
}

DEV void split2(float x, short& hi, short& lo) {
  hi = f2bf(x);
  lo = f2bf(x - bf2f(hi));
}

DEV float sigf(float x) {
  return 1.0f / (1.0f + exp2f(x * -1.44269504f));
}

DEV float tanhf2(float x) {
  float e = exp2f(fmaxf(x, -18.0f) * -2.88539008f);
  return (1.0f - e) / (1.0f + e);
}

DEV void mfma16(f32x4& d, s16x8 a, s16x8 b) {
  asm("v_mfma_f32_16x16x32_bf16 %0, %1, %2, %0" : "+v"(d) : "v"(a), "v"(b));
}

// ---- warmup weights: WT2[n][k2]: [Wk_hi(128)|Wr_hi(512)|Wk_lo(128)|Wr_lo(512)] ----
__global__ __launch_bounds__(256)
void prep_w2(const float* __restrict__ Wk, const float* __restrict__ Wr,
             short* __restrict__ WT2) {
  __shared__ float t[64 * 65];
  const int k0 = blockIdx.x * 64, n0 = blockIdx.y * 64;
  const int c = threadIdx.x & 63, r4 = threadIdx.x >> 6;
#pragma unroll
  for (int i = 0; i < 16; ++i) {
    int r = r4 * 16 + i;
    int k = k0 + r, n = n0 + c;
    t[r * 65 + c] = (k < 128) ? Wk[(size_t)k * 2048 + n] : Wr[(size_t)(k - 128) * 2048 + n];
  }
  __syncthreads();
#pragma unroll
  for (int i = 0; i < 16; ++i) {
    int nn = r4 * 16 + i;
    float v = t[c * 65 + nn];
    short hi, lo; split2(v, hi, lo);
    WT2[(size_t)(n0 + nn) * 1280 + k0 + c] = hi;
    WT2[(size_t)(n0 + nn) * 1280 + 640 + k0 + c] = lo;
  }
}

// ---- WdecAll rows 0..2047: Wdec = Wr + Wd@Wk (f32), split hi|lo over K=512 ----
__global__ __launch_bounds__(256)
void wdec_split(const float* __restrict__ Wd, const float* __restrict__ Wk,
                const float* __restrict__ Wr, short* __restrict__ WdecAll) {
  const int n = blockIdx.x * 256 + threadIdx.x;  // 0..2047
  const int kp = blockIdx.y;                     // 0..511
  float acc = Wr[(size_t)kp * 2048 + n];
#pragma unroll 8
  for (int j = 0; j < 128; ++j)
    acc = fmaf(Wd[(size_t)kp * 128 + j], Wk[(size_t)j * 2048 + n], acc);
  short hi, lo; split2(acc, hi, lo);
  WdecAll[(size_t)n * 1024 + kp] = hi;
  WdecAll[(size_t)n * 1024 + 512 + kp] = lo;
}

// ---- WdecAll rows 2048..2175: Wd columns ----
__global__ __launch_bounds__(256)
void wd_append(const float* __restrict__ Wd, short* __restrict__ WdecAll) {
  const int t = blockIdx.x * 256 + threadIdx.x;  // 0..65535
  const int k = t >> 7, n = t & 127;
  float v = Wd[(size_t)k * 128 + n];
  short hi, lo; split2(v, hi, lo);
  WdecAll[(size_t)(2048 + n) * 1024 + k] = hi;
  WdecAll[(size_t)(2048 + n) * 1024 + 512 + k] = lo;
}

// ---- bdecAll[0..2047] = b + bd@Wk ; [2048..2175] = bd ----
__global__ __launch_bounds__(256)
void bdec_all(const float* __restrict__ bd, const float* __restrict__ Wk,
              const float* __restrict__ b, float* __restrict__ bdecAll) {
  const int n = blockIdx.x * 256 + threadIdx.x;
  if (n < 2048) {
    float acc = b[n];
#pragma unroll 8
    for (int j = 0; j < 128; ++j) acc = fmaf(bd[j], Wk[(size_t)j * 2048 + n], acc);
    bdecAll[n] = acc;
  } else if (n < 2176) {
    bdecAll[n] = bd[n - 2048];
  }
}

// ---- x0 init: inputs[:,0,:] -> AW0 cols [0..127]=hi, [640..767]=lo ----
__global__ __launch_bounds__(256)
void x0_init(const float* __restrict__ inputs, short* __restrict__ AW0) {
  const int t = blockIdx.x * 256 + threadIdx.x;  // 16384
  const int r = t >> 4, c0 = (t & 15) * 8;
  const float* src = inputs + (size_t)r * 16384 + c0;
  floatx4 a = *(const floatx4*)src;
  floatx4 b = *(const floatx4*)(src + 4);
  s16x8 vh, vl;
#pragma unroll
  for (int e = 0; e < 8; ++e) {
    float x = (e < 4) ? a[e] : b[e - 4];
    short hi, lo; split2(x, hi, lo);
    vh[e] = hi; vl[e] = lo;
  }
  *(s16x8*)(AW0 + (size_t)r * 1280 + c0) = vh;
  *(s16x8*)(AW0 + (size_t)r * 1280 + 640 + c0) = vl;
}

// ---------------- persistent LSTM: all 224 steps in one kernel ----------------
// grid 272, __launch_bounds__(256,2) -> all blocks co-resident.
// blocks 0..255: gate blocks (16 m-blocks x 16 XCD-local u-strips).
// blocks 256..271: proj blocks (active in decode: out[:,s-1] = h_{s-1}@Wd + bd).
// A buffers: AW0/AW1 ping-pong, row stride 1280: [x_hi(128)|h_hi(512)|x_lo(128)|h_lo(512)].
// warm t: A=AW[t&1] (full 1280 K); decode t: A=h-cols of AW[t&1] (K=1024).
// grid barrier per step: syncthreads (vmcnt drain) + threadfence/atomics (agent scope).
__global__ __launch_bounds__(256, 2)
void lstm_persist(const float* __restrict__ inputs,
                  const short* __restrict__ WT2,
                  const short* __restrict__ WdecAll,
                  const float* __restrict__ bias0,
                  const float* __restrict__ bdecA,
                  short* __restrict__ AW0, short* __restrict__ AW1,
                  float* __restrict__ Cst,
                  float* __restrict__ out, int S,
                  unsigned* __restrict__ sync) {
  __shared__ char lds[73728];  // A ring 3x8KB @0; B ring 3x16KB @24576
  const int tid = threadIdx.x;
  const int lane = tid & 63;
  const int wid = tid >> 6;
  const int wm = wid & 1, wu = wid >> 1;
  const int bid = blockIdx.x;
  const bool is16 = (bid >= 256);
  int m0, u0;
  if (is16) {
    m0 = (bid - 256) * 64; u0 = 0;
  } else {
    const int jb = bid >> 3;
    const int strip = (bid & 7) + ((jb >> 4) << 3);  // XCD-local strips
    m0 = (jb & 15) * 64;
    u0 = strip * 32;
  }
  const int wbase = (tid & 192) * 16;
  const bool xconv = (!is16 && u0 == 0);
  unsigned* cnt = sync;
  unsigned* gen = sync + 32;

  for (int t = 0; t < 224; ++t) {
    const bool warm = (t < 128);
    const int s = t - 127;                 // decode step index (1..96)
    const int nkt = warm ? 20 : 16;
    const int kp = warm ? 1280 : 1024;     // W row stride
    const short* W = warm ? WT2 : WdecAll;
    const float* bs = warm ? bias0 : bdecA;
    const short* Ain = (t & 1) ? AW1 : AW0;
    short* hout = ((t + 1) & 1) ? AW1 : AW0;
    const bool gate_on = !is16 && (warm || s <= 95);
    const bool active = gate_on || (is16 && !warm);

    if (active) {
      auto stage = [&](int kt, int bsel) {
        char* B = lds + 24576 + bsel * 16384;
#pragma unroll
        for (int p = 0; p < 4; ++p) {
          int idx = p * 256 + tid;
          int r = idx >> 3, jp = idx & 7;
          int j = jp ^ (r & 7);
          int gu = is16 ? (2048 + r) : (((r >> 5) << 9) + u0 + (r & 31));
          gld_lds16(W + (size_t)gu * kp + kt * 64 + j * 8, B + p * 4096 + wbase);
        }
        char* A = lds + bsel * 8192;
        const int ka = warm ? kt * 64
                            : ((kt < 8) ? (128 + kt * 64) : (768 + (kt - 8) * 64));
#pragma unroll
        for (int p = 0; p < 2; ++p) {
          int idx = p * 256 + tid;
          int r = idx >> 3, jp = idx & 7;
          int j = jp ^ (r & 7);
          gld_lds16(Ain + (size_t)(m0 + r) * 1280 + ka + j * 8, A + p * 4096 + wbase);
        }
      };

      f32x4 acc[2][4] = {};
      stage(0, 0);
      stage(1, 1);
      int sl = 0;
      for (int kt = 0; kt < nkt; ++kt) {
        if (kt < nkt - 1) WAITVM(6);
        else WAITVM(0);
        barrier_pipe();
        if (kt + 2 < nkt) stage(kt + 2, (sl >= 1) ? sl - 1 : 2);
        const char* A = lds + sl * 8192;
        const char* B = lds + 24576 + sl * 16384;
#pragma unroll
        for (int s2 = 0; s2 < 2; ++s2) {
          const int jd = s2 * 4 + (lane >> 4);
          s16x8 av[2], bv[4];
#pragma unroll
          for (int mi = 0; mi < 2; ++mi) {
            int r = wm * 32 + mi * 16 + (lane & 15);
            av[mi] = *(const s16x8*)(A + r * 128 + ((jd ^ (r & 7)) << 4));
          }
#pragma unroll
          for (int g = 0; g < 4; ++g) {
            int rB = g * 32 + wu * 16 + (lane & 15);
            bv[g] = *(const s16x8*)(B + rB * 128 + ((jd ^ (rB & 7)) << 4));
          }
#pragma unroll
          for (int mi = 0; mi < 2; ++mi)
#pragma unroll
            for (int g = 0; g < 4; ++g) mfma16(acc[mi][g], av[mi], bv[g]);
        }
        sl = (sl == 2) ? 0 : sl + 1;
      }

      asm volatile("s_nop 7\ns_nop 7\ns_nop 7");

      if (is16) {
        // projection epilogue -> out[:, s-1]
#pragma unroll
        for (int g = 0; g < 4; ++g) {
          const int n = g * 32 + wu * 16 + (lane & 15);
          const float bb = bdecA[2048 + n];
#pragma unroll
          for (int mi = 0; mi < 2; ++mi) {
#pragma unroll
            for (int rr = 0; rr < 4; ++rr) {
              const int m = m0 + wm * 32 + mi * 16 + ((lane >> 4) << 2) + rr;
              out[(size_t)m * ((size_t)S * 128) + (size_t)(s - 1) * 128 + n] =
                  acc[mi][g][rr] + bb;
            }
          }
        }
      } else {
        // gate epilogue
        const int u = u0 + wu * 16 + (lane & 15);
        const float bi = bs[u], bf_ = bs[512 + u], bg = bs[1024 + u], bo = bs[1536 + u];
#pragma unroll
        for (int mi = 0; mi < 2; ++mi) {
#pragma unroll
          for (int rr = 0; rr < 4; ++rr) {
            const int m = m0 + wm * 32 + mi * 16 + ((lane >> 4) << 2) + rr;
            const size_t off = (size_t)m * 512 + u;
            float ig = sigf(acc[mi][0][rr] + bi);
            float fg = sigf(acc[mi][1][rr] + bf_);
            float gg = tanhf2(acc[mi][2][rr] + bg);
            float og = sigf(acc[mi][3][rr] + bo);
            float cn = fg * Cst[off] + ig * gg;
            Cst[off] = cn;
            float hv = og * tanhf2(cn);
            short hh, hl; split2(hv, hh, hl);
            hout[(size_t)m * 1280 + 128 + u] = hh;
            hout[(size_t)m * 1280 + 768 + u] = hl;
          }
        }
        // next-x conversion (warmup only, strip-0 blocks cover all m)
        if (warm && t < 127 && xconv) {
          const float* xn = inputs + (size_t)(t + 1) * 128;
          const int r = tid >> 2;
          const int c0 = (tid & 3) * 32;
          const float* src = xn + (size_t)(m0 + r) * 16384 + c0;
          short* dst = hout + (size_t)(m0 + r) * 1280;
#pragma unroll
          for (int j = 0; j < 32; j += 8) {
            floatx4 a = *(const floatx4*)(src + j);
            floatx4 b = *(const floatx4*)(src + j + 4);
            s16x8 vh, vl;
#pragma unroll
            for (int e = 0; e < 8; ++e) {
              float x = (e < 4) ? a[e] : b[e - 4];
              short hi, lo; split2(x, hi, lo);
              vh[e] = hi; vl[e] = lo;
            }
            *(s16x8*)(dst + c0 + j) = vh;
            *(s16x8*)(dst + 640 + c0 + j) = vl;
          }
        }
      }
    }  // active

    // ---- grid barrier (release/acquire, placement-independent) ----
    __syncthreads();  // compiler drains vmcnt(0): all threads' stores complete
    if (tid == 0) {
      __threadfence();  // release: wbL2
      unsigned a = __hip_atomic_fetch_add(cnt, 1u, __ATOMIC_ACQ_REL,
                                          __HIP_MEMORY_SCOPE_AGENT);
      if (a == (unsigned)(272 * (t + 1) - 1)) {
        __hip_atomic_store(gen, (unsigned)(t + 1), __ATOMIC_RELEASE,
                           __HIP_MEMORY_SCOPE_AGENT);
      } else {
        unsigned g;
        do {
          __builtin_amdgcn_s_sleep(8);
          g = __hip_atomic_load(gen, __ATOMIC_RELAXED, __HIP_MEMORY_SCOPE_AGENT);
        } while (g < (unsigned)(t + 1));
      }
      __threadfence();  // acquire: inv (fresh h for next step)
    }
    __syncthreads();
  }
}

extern "C" void kernel_launch(void* const* d_in, const int* in_sizes, int n_in,
                              void* d_out, int out_size, void* d_ws, size_t ws_size,
                              hipStream_t stream) {
  const float* inputs = (const float*)d_in[0];  // [1024,128,128]
  const float* Wk = (const float*)d_in[1];      // [128,2048]
  const float* Wr = (const float*)d_in[2];      // [512,2048]
  const float* bias = (const float*)d_in[3];    // [2048]
  const float* Wd = (const float*)d_in[4];      // [512,128]
  const float* bd = (const float*)d_in[5];      // [128]
  float* out = (float*)d_out;                   // [1024, S, 128]
  const int S = out_size / (1024 * 128);        // 96

  char* w = (char*)d_ws;
  short* WT2     = (short*)w; w += (size_t)2048 * 1280 * 2;  // 5.24 MB
  short* WdecAll = (short*)w; w += (size_t)2176 * 1024 * 2;  // 4.46 MB
  float* bdecA   = (float*)w; w += (size_t)2176 * 4;
  short* AW0 = (short*)w; w += (size_t)1024 * 1280 * 2;      // 2.62 MB
  short* AW1 = (short*)w; w += (size_t)1024 * 1280 * 2;      // 2.62 MB
  float* Cst = (float*)w; w += (size_t)1024 * 512 * 4;       // 2.10 MB
  unsigned* sync = (unsigned*)w; w += 256;
  if ((size_t)(w - (char*)d_ws) > ws_size) return;           // clean fail

  hipMemsetAsync(AW0, 0, (size_t)1024 * 1280 * 2, stream);
  hipMemsetAsync(Cst, 0, (size_t)1024 * 512 * 4, stream);
  hipMemsetAsync(sync, 0, 256, stream);

  prep_w2<<<dim3(10, 32), 256, 0, stream>>>(Wk, Wr, WT2);
  wdec_split<<<dim3(8, 512), 256, 0, stream>>>(Wd, Wk, Wr, WdecAll);
  wd_append<<<256, 256, 0, stream>>>(Wd, WdecAll);
  bdec_all<<<9, 256, 0, stream>>>(bd, Wk, bias, bdecA);
  x0_init<<<64, 256, 0, stream>>>(inputs, AW0);

  lstm_persist<<<272, 256, 0, stream>>>(inputs, WT2, WdecAll, bias, bdecA,
                                        AW0, AW1, Cst, out, S, sync);
}

// Round 7
// 5089.320 us; speedup vs baseline: 1.4026x; 1.4026x over previous
//
#include <hip/hip_runtime.h>
#include <hip/hip_bf16.h>

typedef float f32x4 __attribute__((ext_vector_type(4)));
typedef short s16x8 __attribute__((ext_vector_type(8)));
typedef float floatx4 __attribute__((ext_vector_type(4)));

#define DEV static __device__ __forceinline__
#define WAITVM(N) asm volatile("s_waitcnt vmcnt(" #N ")" ::: "memory")

DEV void barrier_pipe() {
  __builtin_amdgcn_sched_barrier(0);
  __builtin_amdgcn_s_barrier();
  __builtin_amdgcn_sched_barrier(0);
}

// cached staging (weights: L2-resident across steps)
DEV void gld_lds16(const void* g, void* l) {
  __builtin_amdgcn_global_load_lds(
      (const __attribute__((address_space(1))) void*)g,
      (__attribute__((address_space(3))) void*)l, 16, 0, 0);
}
// coherent staging (activations: bypass L1/L2, read from coherence point)
DEV void gld_lds16_sys(const void* g, void* l) {
  __builtin_amdgcn_global_load_lds(
      (const __attribute__((address_space(1))) void*)g,
      (__attribute__((address_space(3))) void*)l, 16, 0, 17 /*sc0|sc1*/);
}

DEV void st_sys(unsigned* p, unsigned v) {
  __hip_atomic_store(p, v, __ATOMIC_RELAXED, __HIP_MEMORY_SCOPE_SYSTEM);
}
DEV unsigned ld_sys(unsigned* p) {
  return __hip_atomic_load(p, __ATOMIC_RELAXED, __HIP_MEMORY_SCOPE_SYSTEM);
}

DEV short f2bf(float x) {
  union { __hip_bfloat16 h; short s; } u;
  u.h = __float2bfloat16(x);
  return u.s;
}

DEV float bf2f(short s) {
  union { unsigned u; float f; } v;
  v.u = ((unsigned)(unsigned short)s) << 16;
  return v.f;
}

DEV void split2(float x, short& hi, short& lo) {
  hi = f2bf(x);
  lo = f2bf(x - bf2f(hi));
}

DEV unsigned packsplit(float x) {
  short hi, lo; split2(x, hi, lo);
  return (unsigned)(unsigned short)hi | ((unsigned)(unsigned short)lo << 16);
}

DEV float sigf(float x) {
  return 1.0f / (1.0f + exp2f(x * -1.44269504f));
}

DEV float tanhf2(float x) {
  float e = exp2f(fmaxf(x, -18.0f) * -2.88539008f);
  return (1.0f - e) / (1.0f + e);
}

DEV void mfma16(f32x4& d, s16x8 a, s16x8 b) {
  asm("v_mfma_f32_16x16x32_bf16 %0, %1, %2, %0" : "+v"(d) : "v"(a), "v"(b));
}

// K layout (interleaved hi/lo pairs):
// warm  K'=1280: cols 2k/2k+1 = hi/lo of [Wk(128)|Wr(512)] combined k
// decode K'=1024: cols 2k/2k+1 = hi/lo of k<512
// ---- warm weights WT2[n][1280] ----
__global__ __launch_bounds__(256)
void prep_w2(const float* __restrict__ Wk, const float* __restrict__ Wr,
             short* __restrict__ WT2) {
  __shared__ float t[64 * 65];
  const int k0 = blockIdx.x * 64, n0 = blockIdx.y * 64;
  const int c = threadIdx.x & 63, r4 = threadIdx.x >> 6;
#pragma unroll
  for (int i = 0; i < 16; ++i) {
    int r = r4 * 16 + i;
    int k = k0 + r, n = n0 + c;
    t[r * 65 + c] = (k < 128) ? Wk[(size_t)k * 2048 + n] : Wr[(size_t)(k - 128) * 2048 + n];
  }
  __syncthreads();
#pragma unroll
  for (int i = 0; i < 16; ++i) {
    int nn = r4 * 16 + i;
    float v = t[c * 65 + nn];
    short hi, lo; split2(v, hi, lo);
    WT2[(size_t)(n0 + nn) * 1280 + 2 * (k0 + c)] = hi;
    WT2[(size_t)(n0 + nn) * 1280 + 2 * (k0 + c) + 1] = lo;
  }
}

// ---- WdecAll rows 0..2047: Wdec = Wr + Wd@Wk (f32), interleaved pairs ----
__global__ __launch_bounds__(256)
void wdec_split(const float* __restrict__ Wd, const float* __restrict__ Wk,
                const float* __restrict__ Wr, short* __restrict__ WdecAll) {
  const int n = blockIdx.x * 256 + threadIdx.x;  // 0..2047
  const int kp = blockIdx.y;                     // 0..511
  float acc = Wr[(size_t)kp * 2048 + n];
#pragma unroll 8
  for (int j = 0; j < 128; ++j)
    acc = fmaf(Wd[(size_t)kp * 128 + j], Wk[(size_t)j * 2048 + n], acc);
  short hi, lo; split2(acc, hi, lo);
  WdecAll[(size_t)n * 1024 + 2 * kp] = hi;
  WdecAll[(size_t)n * 1024 + 2 * kp + 1] = lo;
}

// ---- WdecAll rows 2048..2175: Wd columns, interleaved pairs ----
__global__ __launch_bounds__(256)
void wd_append(const float* __restrict__ Wd, short* __restrict__ WdecAll) {
  const int t = blockIdx.x * 256 + threadIdx.x;  // 0..65535
  const int k = t >> 7, n = t & 127;
  float v = Wd[(size_t)k * 128 + n];
  short hi, lo; split2(v, hi, lo);
  WdecAll[(size_t)(2048 + n) * 1024 + 2 * k] = hi;
  WdecAll[(size_t)(2048 + n) * 1024 + 2 * k + 1] = lo;
}

// ---- bdecAll[0..2047] = b + bd@Wk ; [2048..2175] = bd ----
__global__ __launch_bounds__(256)
void bdec_all(const float* __restrict__ bd, const float* __restrict__ Wk,
              const float* __restrict__ b, float* __restrict__ bdecAll) {
  const int n = blockIdx.x * 256 + threadIdx.x;
  if (n < 2048) {
    float acc = b[n];
#pragma unroll 8
    for (int j = 0; j < 128; ++j) acc = fmaf(bd[j], Wk[(size_t)j * 2048 + n], acc);
    bdecAll[n] = acc;
  } else if (n < 2176) {
    bdecAll[n] = bd[n - 2048];
  }
}

// ---- x0 init: inputs[:,0,:] -> AW0 uint-cols 0..127 (packed hi|lo) ----
__global__ __launch_bounds__(256)
void x0_init(const float* __restrict__ inputs, short* __restrict__ AW0) {
  const int t = blockIdx.x * 256 + threadIdx.x;  // 16384
  const int r = t >> 4, c0 = (t & 15) * 8;
  const float* src = inputs + (size_t)r * 16384 + c0;
  unsigned* du = (unsigned*)(AW0 + (size_t)r * 1280);
  floatx4 a = *(const floatx4*)src;
  floatx4 b = *(const floatx4*)(src + 4);
#pragma unroll
  for (int e = 0; e < 8; ++e)
    du[c0 + e] = packsplit((e < 4) ? a[e] : b[e - 4]);
}

// ---------------- persistent LSTM: all 224 steps, no L2 invalidation ----------------
// grid 272 = 256 gate blocks (16 m x 16 XCD-local u-strips) + 16 proj blocks.
// A rows (shorts, stride 1280): [x pairs 0..255 | h pairs 256..1279]. decode reads @256.
// h written as packed uint system-scope stores; A staged with sc0|sc1 bypass loads;
// weights staged with cached loads (L2-resident). C lives in registers.
__global__ __launch_bounds__(256, 2)
void lstm_persist(const float* __restrict__ inputs,
                  const short* __restrict__ WT2,
                  const short* __restrict__ WdecAll,
                  const float* __restrict__ bias0,
                  const float* __restrict__ bdecA,
                  short* __restrict__ AW0, short* __restrict__ AW1,
                  float* __restrict__ out, int S,
                  unsigned* __restrict__ sync) {
  __shared__ char lds[73728];  // A ring 3x8KB @0; B ring 3x16KB @24576
  const int tid = threadIdx.x;
  const int lane = tid & 63;
  const int wid = tid >> 6;
  const int wm = wid & 1, wu = wid >> 1;
  const int bid = blockIdx.x;
  const bool is16 = (bid >= 256);
  int m0, u0;
  if (is16) {
    m0 = (bid - 256) * 64; u0 = 0;
  } else {
    const int jb = bid >> 3;
    const int strip = (bid & 7) + ((jb >> 4) << 3);  // XCD-local strips
    m0 = (jb & 15) * 64;
    u0 = strip * 32;
  }
  const int wbase = (tid & 192) * 16;
  const bool xconv = (!is16 && u0 == 0);
  unsigned* slots = sync;        // 272 slots, 1 uint each (own 4B; fine)
  unsigned* gen = sync + 512;

  float creg[2][4] = {};  // persistent cell state (gate blocks only)

  for (int t = 0; t < 224; ++t) {
    const bool warm = (t < 128);
    const int s = t - 127;               // decode step index (1..96)
    const int nkt = warm ? 20 : 16;
    const int kp = warm ? 1280 : 1024;   // W row stride
    const short* W = warm ? WT2 : WdecAll;
    const float* bs = warm ? bias0 : bdecA;
    const short* Ain = ((t & 1) ? AW1 : AW0) + (warm ? 0 : 256);
    short* hout = ((t + 1) & 1) ? AW1 : AW0;
    const bool gate_on = !is16 && (warm || s <= 95);
    const bool active = gate_on || (is16 && !warm);

    if (active) {
      auto stage = [&](int kt, int bsel) {
        char* B = lds + 24576 + bsel * 16384;
#pragma unroll
        for (int p = 0; p < 4; ++p) {
          int idx = p * 256 + tid;
          int r = idx >> 3, jp = idx & 7;
          int j = jp ^ (r & 7);
          int gu = is16 ? (2048 + r) : (((r >> 5) << 9) + u0 + (r & 31));
          gld_lds16(W + (size_t)gu * kp + kt * 64 + j * 8, B + p * 4096 + wbase);
        }
        char* A = lds + bsel * 8192;
#pragma unroll
        for (int p = 0; p < 2; ++p) {
          int idx = p * 256 + tid;
          int r = idx >> 3, jp = idx & 7;
          int j = jp ^ (r & 7);
          gld_lds16_sys(Ain + (size_t)(m0 + r) * 1280 + kt * 64 + j * 8,
                        A + p * 4096 + wbase);
        }
      };

      f32x4 acc[2][4] = {};
      stage(0, 0);
      stage(1, 1);
      int sl = 0;
      for (int kt = 0; kt < nkt; ++kt) {
        if (kt < nkt - 1) WAITVM(6);
        else WAITVM(0);
        barrier_pipe();
        if (kt + 2 < nkt) stage(kt + 2, (sl >= 1) ? sl - 1 : 2);
        const char* A = lds + sl * 8192;
        const char* B = lds + 24576 + sl * 16384;
#pragma unroll
        for (int s2 = 0; s2 < 2; ++s2) {
          const int jd = s2 * 4 + (lane >> 4);
          s16x8 av[2], bv[4];
#pragma unroll
          for (int mi = 0; mi < 2; ++mi) {
            int r = wm * 32 + mi * 16 + (lane & 15);
            av[mi] = *(const s16x8*)(A + r * 128 + ((jd ^ (r & 7)) << 4));
          }
#pragma unroll
          for (int g = 0; g < 4; ++g) {
            int rB = g * 32 + wu * 16 + (lane & 15);
            bv[g] = *(const s16x8*)(B + rB * 128 + ((jd ^ (rB & 7)) << 4));
          }
#pragma unroll
          for (int mi = 0; mi < 2; ++mi)
#pragma unroll
            for (int g = 0; g < 4; ++g) mfma16(acc[mi][g], av[mi], bv[g]);
        }
        sl = (sl == 2) ? 0 : sl + 1;
      }

      asm volatile("s_nop 7\ns_nop 7\ns_nop 7");

      if (is16) {
        // projection epilogue -> out[:, s-1]
#pragma unroll
        for (int g = 0; g < 4; ++g) {
          const int n = g * 32 + wu * 16 + (lane & 15);
          const float bb = bdecA[2048 + n];
#pragma unroll
          for (int mi = 0; mi < 2; ++mi) {
#pragma unroll
            for (int rr = 0; rr < 4; ++rr) {
              const int m = m0 + wm * 32 + mi * 16 + ((lane >> 4) << 2) + rr;
              out[(size_t)m * ((size_t)S * 128) + (size_t)(s - 1) * 128 + n] =
                  acc[mi][g][rr] + bb;
            }
          }
        }
      } else {
        // gate epilogue; h -> packed uint system store; C in registers
        const int u = u0 + wu * 16 + (lane & 15);
        const float bi = bs[u], bf_ = bs[512 + u], bg = bs[1024 + u], bo = bs[1536 + u];
#pragma unroll
        for (int mi = 0; mi < 2; ++mi) {
#pragma unroll
          for (int rr = 0; rr < 4; ++rr) {
            const int m = m0 + wm * 32 + mi * 16 + ((lane >> 4) << 2) + rr;
            float ig = sigf(acc[mi][0][rr] + bi);
            float fg = sigf(acc[mi][1][rr] + bf_);
            float gg = tanhf2(acc[mi][2][rr] + bg);
            float og = sigf(acc[mi][3][rr] + bo);
            float cn = fg * creg[mi][rr] + ig * gg;
            creg[mi][rr] = cn;
            float hv = og * tanhf2(cn);
            st_sys((unsigned*)(hout + (size_t)m * 1280) + 128 + u, packsplit(hv));
          }
        }
        // next-x conversion (warmup only; strip-0 blocks cover all m)
        if (warm && t < 127 && xconv) {
          const float* xn = inputs + (size_t)(t + 1) * 128;
          const int r = tid >> 2;
          const int c0 = (tid & 3) * 32;
          const float* src = xn + (size_t)(m0 + r) * 16384 + c0;
          unsigned* du = (unsigned*)(hout + (size_t)(m0 + r) * 1280);
#pragma unroll
          for (int j = 0; j < 32; j += 8) {
            floatx4 a = *(const floatx4*)(src + j);
            floatx4 b = *(const floatx4*)(src + j + 4);
#pragma unroll
            for (int e = 0; e < 8; ++e)
              st_sys(du + c0 + j + e, packsplit((e < 4) ? a[e] : b[e - 4]));
          }
        }
      }
    }  // active

    if (t == 223) break;

    // ---- grid barrier: no fences, no L2 wb/inv ----
    __syncthreads();  // drains each thread's vmcnt -> system stores complete
    if (bid == 0) {
      if (tid == 0) st_sys(slots + 0, (unsigned)(t + 1));
      // parallel poll of all 272 slots
      while (ld_sys(slots + tid) < (unsigned)(t + 1)) __builtin_amdgcn_s_sleep(1);
      if (tid < 16)
        while (ld_sys(slots + 256 + tid) < (unsigned)(t + 1)) __builtin_amdgcn_s_sleep(1);
      __syncthreads();
      if (tid == 0) st_sys(gen, (unsigned)(t + 1));
    } else {
      if (tid == 0) {
        st_sys(slots + bid, (unsigned)(t + 1));
        while (ld_sys(gen) < (unsigned)(t + 1)) __builtin_amdgcn_s_sleep(2);
      }
      __syncthreads();
    }
  }
}

extern "C" void kernel_launch(void* const* d_in, const int* in_sizes, int n_in,
                              void* d_out, int out_size, void* d_ws, size_t ws_size,
                              hipStream_t stream) {
  const float* inputs = (const float*)d_in[0];  // [1024,128,128]
  const float* Wk = (const float*)d_in[1];      // [128,2048]
  const float* Wr = (const float*)d_in[2];      // [512,2048]
  const float* bias = (const float*)d_in[3];    // [2048]
  const float* Wd = (const float*)d_in[4];      // [512,128]
  const float* bd = (const float*)d_in[5];      // [128]
  float* out = (float*)d_out;                   // [1024, S, 128]
  const int S = out_size / (1024 * 128);        // 96

  char* w = (char*)d_ws;
  short* WT2     = (short*)w; w += (size_t)2048 * 1280 * 2;  // 5.24 MB
  short* WdecAll = (short*)w; w += (size_t)2176 * 1024 * 2;  // 4.46 MB
  float* bdecA   = (float*)w; w += (size_t)2176 * 4;
  short* AW0 = (short*)w; w += (size_t)1024 * 1280 * 2;      // 2.62 MB
  short* AW1 = (short*)w; w += (size_t)1024 * 1280 * 2;      // 2.62 MB
  unsigned* sync = (unsigned*)w; w += 4096;
  if ((size_t)(w - (char*)d_ws) > ws_size) return;           // clean fail

  hipMemsetAsync(AW0, 0, (size_t)1024 * 1280 * 2, stream);
  hipMemsetAsync(sync, 0, 4096, stream);

  prep_w2<<<dim3(10, 32), 256, 0, stream>>>(Wk, Wr, WT2);
  wdec_split<<<dim3(8, 512), 256, 0, stream>>>(Wd, Wk, Wr, WdecAll);
  wd_append<<<256, 256, 0, stream>>>(Wd, WdecAll);
  bdec_all<<<9, 256, 0, stream>>>(bd, Wk, bias, bdecA);
  x0_init<<<64, 256, 0, stream>>>(inputs, AW0);

  lstm_persist<<<272, 256, 0, stream>>>(inputs, WT2, WdecAll, bias, bdecA,
                                        AW0, AW1, out, S, sync);
}

// Round 10
// 3613.066 us; speedup vs baseline: 1.9757x; 1.4086x over previous
//
#include <hip/hip_runtime.h>
#include <hip/hip_bf16.h>

typedef float f32x4 __attribute__((ext_vector_type(4)));
typedef short s16x8 __attribute__((ext_vector_type(8)));
typedef float floatx4 __attribute__((ext_vector_type(4)));

#define DEV static __device__ __forceinline__
#define WAITVM(N) asm volatile("s_waitcnt vmcnt(" #N ")" ::: "memory")

DEV void barrier_pipe() {
  __builtin_amdgcn_sched_barrier(0);
  __builtin_amdgcn_s_barrier();
  __builtin_amdgcn_sched_barrier(0);
}

DEV void gld_lds16(const void* g, void* l) {
  __builtin_amdgcn_global_load_lds(
      (const __attribute__((address_space(1))) void*)g,
      (__attribute__((address_space(3))) void*)l, 16, 0, 0);
}

DEV short f2bf(float x) {
  union { __hip_bfloat16 h; short s; } u;
  u.h = __float2bfloat16(x);
  return u.s;
}

DEV float bf2f(short s) {
  union { unsigned u; float f; } v;
  v.u = ((unsigned)(unsigned short)s) << 16;
  return v.f;
}

DEV void split2(float x, short& hi, short& lo) {
  hi = f2bf(x);
  lo = f2bf(x - bf2f(hi));
}

DEV float sigf(float x) {
  return 1.0f / (1.0f + exp2f(x * -1.44269504f));
}

DEV float tanhf2(float x) {
  float e = exp2f(fmaxf(x, -18.0f) * -2.88539008f);
  return (1.0f - e) / (1.0f + e);
}

DEV void mfma16(f32x4& d, s16x8 a, s16x8 b) {
  asm("v_mfma_f32_16x16x32_bf16 %0, %1, %2, %0" : "+v"(d) : "v"(a), "v"(b));
}

// ---- warm weights WT2[n][1280]: [Wk_hi(128)|Wr_hi(512)|Wk_lo(128)|Wr_lo(512)] ----
__global__ __launch_bounds__(256)
void prep_w2(const float* __restrict__ Wk, const float* __restrict__ Wr,
             short* __restrict__ WT2) {
  __shared__ float t[64 * 65];
  const int k0 = blockIdx.x * 64, n0 = blockIdx.y * 64;
  const int c = threadIdx.x & 63, r4 = threadIdx.x >> 6;
#pragma unroll
  for (int i = 0; i < 16; ++i) {
    int r = r4 * 16 + i;
    int k = k0 + r, n = n0 + c;
    t[r * 65 + c] = (k < 128) ? Wk[(size_t)k * 2048 + n] : Wr[(size_t)(k - 128) * 2048 + n];
  }
  __syncthreads();
#pragma unroll
  for (int i = 0; i < 16; ++i) {
    int nn = r4 * 16 + i;
    float v = t[c * 65 + nn];
    short hi, lo; split2(v, hi, lo);
    WT2[(size_t)(n0 + nn) * 1280 + k0 + c] = hi;
    WT2[(size_t)(n0 + nn) * 1280 + 640 + k0 + c] = lo;
  }
}

// ---- WdecAll rows 0..2047: Wdec = Wr + Wd@Wk (f32), [hi(512)|lo(512)] ----
__global__ __launch_bounds__(256)
void wdec_split(const float* __restrict__ Wd, const float* __restrict__ Wk,
                const float* __restrict__ Wr, short* __restrict__ WdecAll) {
  const int n = blockIdx.x * 256 + threadIdx.x;  // 0..2047
  const int kp = blockIdx.y;                     // 0..511
  float acc = Wr[(size_t)kp * 2048 + n];
#pragma unroll 8
  for (int j = 0; j < 128; ++j)
    acc = fmaf(Wd[(size_t)kp * 128 + j], Wk[(size_t)j * 2048 + n], acc);
  short hi, lo; split2(acc, hi, lo);
  WdecAll[(size_t)n * 1024 + kp] = hi;
  WdecAll[(size_t)n * 1024 + 512 + kp] = lo;
}

// ---- WdecAll rows 2048..2175: Wd columns ----
__global__ __launch_bounds__(256)
void wd_append(const float* __restrict__ Wd, short* __restrict__ WdecAll) {
  const int t = blockIdx.x * 256 + threadIdx.x;  // 0..65535
  const int k = t >> 7, n = t & 127;
  float v = Wd[(size_t)k * 128 + n];
  short hi, lo; split2(v, hi, lo);
  WdecAll[(size_t)(2048 + n) * 1024 + k] = hi;
  WdecAll[(size_t)(2048 + n) * 1024 + 512 + k] = lo;
}

// ---- bdecAll[0..2047] = b + bd@Wk ; [2048..2175] = bd ----
__global__ __launch_bounds__(256)
void bdec_all(const float* __restrict__ bd, const float* __restrict__ Wk,
              const float* __restrict__ b, float* __restrict__ bdecAll) {
  const int n = blockIdx.x * 256 + threadIdx.x;
  if (n < 2048) {
    float acc = b[n];
#pragma unroll 8
    for (int j = 0; j < 128; ++j) acc = fmaf(bd[j], Wk[(size_t)j * 2048 + n], acc);
    bdecAll[n] = acc;
  } else if (n < 2176) {
    bdecAll[n] = bd[n - 2048];
  }
}

// ---- x0 init: inputs[:,0,:] -> AW0 cols [0..128)=hi, [640..768)=lo ----
__global__ __launch_bounds__(256)
void x0_init(const float* __restrict__ inputs, short* __restrict__ AW0) {
  const int t = blockIdx.x * 256 + threadIdx.x;  // 16384
  const int r = t >> 4, c0 = (t & 15) * 8;
  const float* src = inputs + (size_t)r * 16384 + c0;
  floatx4 a = *(const floatx4*)src;
  floatx4 b = *(const floatx4*)(src + 4);
  s16x8 vh, vl;
#pragma unroll
  for (int e = 0; e < 8; ++e) {
    float x = (e < 4) ? a[e] : b[e - 4];
    short hi, lo; split2(x, hi, lo);
    vh[e] = hi; vl[e] = lo;
  }
  *(s16x8*)(AW0 + (size_t)r * 1280 + c0) = vh;
  *(s16x8*)(AW0 + (size_t)r * 1280 + 640 + c0) = vl;
}

// ---------------- LSTM step: 64m x 16u gate blocks, grid 512 (2 blocks/CU) ----------------
// MODE 0 (warm):  grid 512 gate blocks. A=AW (stride 1280), W=WT2, NKT=20.
// MODE 1 (decode):grid 528 = 512 gate (A stride 1024, W=WdecAll) + 16 proj blocks
//                 (64m x 128n, W rows 2048+) writing out[:,sidx,:].
// MODE 2 (final proj): grid 16, proj only.
// 3-ring LDS; block-uniform counted vmcnt: gate 4 loads/thread/stage, proj 6.
// A-staging / compute fragment maps / epilogue: round-5-proven forms.
template <int MODE>
__global__ __launch_bounds__(256)
void lstm_step(const short* __restrict__ Ain, short* __restrict__ hout,
               int hstride, int hioff, int looff,
               const float* __restrict__ xnext,
               float* __restrict__ Cst,
               const short* __restrict__ W2,
               const float* __restrict__ bias,
               float* __restrict__ out, int sidx, int S) {
  constexpr int NKT = (MODE == 0) ? 20 : 16;
  constexpr int ASTR = (MODE == 0) ? 1280 : 1024;  // A row stride == W row stride
  constexpr int LDSZ = (MODE == 0) ? 49152 : 73728;
  __shared__ char lds[LDSZ];
  const int tid = threadIdx.x, lane = tid & 63, wid = tid >> 6;
  const int l15 = lane & 15, l4 = lane >> 4;
  const int bid = blockIdx.x;
  const int wbase = (tid & 192) * 16;
  const bool proj = (MODE == 2) || (MODE == 1 && bid >= 512);

  if (!proj) {
    // -------- gate block: 64 m x 16 u, 4 gates --------
    const int strip = bid & 31;        // 32 strips; strip%8 = XCD (B tile L2-local)
    const int mblk = bid >> 5;         // 16 m-blocks
    const int m0 = mblk * 64;
    const int u0 = strip * 16;

    auto stage = [&](int kt, int bsel) {
      char* B = lds + 24576 + bsel * 8192;
#pragma unroll
      for (int p = 0; p < 2; ++p) {
        int idx = p * 256 + tid;
        int r = idx >> 3, jp = idx & 7;
        int j = jp ^ (r & 7);
        int gu = ((r >> 4) << 9) + u0 + (r & 15);  // gate = r>>4, u = u0 + (r&15)
        gld_lds16(W2 + (size_t)gu * ASTR + kt * 64 + j * 8, B + p * 4096 + wbase);
      }
      char* A = lds + bsel * 8192;
#pragma unroll
      for (int p = 0; p < 2; ++p) {
        int idx = p * 256 + tid;
        int r = idx >> 3, jp = idx & 7;
        int j = jp ^ (r & 7);
        gld_lds16(Ain + (size_t)(m0 + r) * ASTR + kt * 64 + j * 8, A + p * 4096 + wbase);
      }
    };

    f32x4 acc[4] = {};
    stage(0, 0);
    stage(1, 1);
#pragma unroll
    for (int kt = 0; kt < NKT; ++kt) {
      if (kt == NKT - 1) { WAITVM(0); } else { WAITVM(4); }
      barrier_pipe();
      if (kt + 2 < NKT) stage(kt + 2, (kt + 2) % 3);
      const char* A = lds + (kt % 3) * 8192;
      const char* B = lds + 24576 + (kt % 3) * 8192;
#pragma unroll
      for (int s2 = 0; s2 < 2; ++s2) {
        const int jd = s2 * 4 + l4;
        const int r = wid * 16 + l15;
        s16x8 av = *(const s16x8*)(A + r * 128 + ((jd ^ (r & 7)) << 4));
#pragma unroll
        for (int g = 0; g < 4; ++g) {
          const int rB = g * 16 + l15;
          s16x8 bv = *(const s16x8*)(B + rB * 128 + ((jd ^ (rB & 7)) << 4));
          mfma16(acc[g], av, bv);
        }
      }
    }

    asm volatile("s_nop 7\ns_nop 7\ns_nop 7");

    // gate epilogue
    const int u = u0 + l15;
    const float bi = bias[u], bf_ = bias[512 + u], bg = bias[1024 + u], bo = bias[1536 + u];
#pragma unroll
    for (int rr = 0; rr < 4; ++rr) {
      const int m = m0 + wid * 16 + (l4 << 2) + rr;
      const size_t off = (size_t)m * 512 + u;
      float ig = sigf(acc[0][rr] + bi);
      float fg = sigf(acc[1][rr] + bf_);
      float gg = tanhf2(acc[2][rr] + bg);
      float og = sigf(acc[3][rr] + bo);
      float cn = fg * Cst[off] + ig * gg;
      Cst[off] = cn;
      float hv = og * tanhf2(cn);
      short hh, hl; split2(hv, hh, hl);
      hout[(size_t)m * hstride + hioff + u] = hh;
      hout[(size_t)m * hstride + looff + u] = hl;
    }

    // next-x conversion (warmup only; strip-0 blocks cover their 64 m rows)
    if (MODE == 0 && xnext != nullptr && strip == 0) {
      const int r = tid >> 2;
      const int c0 = (tid & 3) * 32;
      const float* src = xnext + (size_t)(m0 + r) * 16384 + c0;
      short* dst = hout + (size_t)(m0 + r) * 1280;
#pragma unroll
      for (int j = 0; j < 32; j += 8) {
        floatx4 a = *(const floatx4*)(src + j);
        floatx4 b = *(const floatx4*)(src + j + 4);
        s16x8 vh, vl;
#pragma unroll
        for (int e = 0; e < 8; ++e) {
          float x = (e < 4) ? a[e] : b[e - 4];
          short hi, lo; split2(x, hi, lo);
          vh[e] = hi; vl[e] = lo;
        }
        *(s16x8*)(dst + c0 + j) = vh;
        *(s16x8*)(dst + 640 + c0 + j) = vl;
      }
    }
  } else {
    // -------- proj block: 64 m x 128 n, K'=1024, W rows 2048.. --------
    const int pb = (MODE == 2) ? bid : bid - 512;
    const int m0 = pb * 64;

    auto stageP = [&](int kt, int bsel) {
      char* B = lds + 24576 + bsel * 16384;
#pragma unroll
      for (int p = 0; p < 4; ++p) {
        int idx = p * 256 + tid;
        int r = idx >> 3, jp = idx & 7;
        int j = jp ^ (r & 7);
        gld_lds16(W2 + (size_t)(2048 + r) * 1024 + kt * 64 + j * 8, B + p * 4096 + wbase);
      }
      char* A = lds + bsel * 8192;
#pragma unroll
      for (int p = 0; p < 2; ++p) {
        int idx = p * 256 + tid;
        int r = idx >> 3, jp = idx & 7;
        int j = jp ^ (r & 7);
        gld_lds16(Ain + (size_t)(m0 + r) * 1024 + kt * 64 + j * 8, A + p * 4096 + wbase);
      }
    };

    f32x4 acc[8] = {};
    stageP(0, 0);
    stageP(1, 1);
#pragma unroll
    for (int kt = 0; kt < 16; ++kt) {
      if (kt == 15) { WAITVM(0); } else { WAITVM(6); }
      barrier_pipe();
      if (kt + 2 < 16) stageP(kt + 2, (kt + 2) % 3);
      const char* A = lds + (kt % 3) * 8192;
      const char* B = lds + 24576 + (kt % 3) * 16384;
#pragma unroll
      for (int s2 = 0; s2 < 2; ++s2) {
        const int jd = s2 * 4 + l4;
        const int r = wid * 16 + l15;
        s16x8 av = *(const s16x8*)(A + r * 128 + ((jd ^ (r & 7)) << 4));
#pragma unroll
        for (int nt = 0; nt < 8; ++nt) {
          const int rB = nt * 16 + l15;
          s16x8 bv = *(const s16x8*)(B + rB * 128 + ((jd ^ (rB & 7)) << 4));
          mfma16(acc[nt], av, bv);
        }
      }
    }

    asm volatile("s_nop 7\ns_nop 7\ns_nop 7");

#pragma unroll
    for (int nt = 0; nt < 8; ++nt) {
      const int n = nt * 16 + l15;
      const float bb = bias[2048 + n];
#pragma unroll
      for (int rr = 0; rr < 4; ++rr) {
        const int m = m0 + wid * 16 + (l4 << 2) + rr;
        out[(size_t)m * ((size_t)S * 128) + (size_t)sidx * 128 + n] = acc[nt][rr] + bb;
      }
    }
  }
}

extern "C" void kernel_launch(void* const* d_in, const int* in_sizes, int n_in,
                              void* d_out, int out_size, void* d_ws, size_t ws_size,
                              hipStream_t stream) {
  const float* inputs = (const float*)d_in[0];  // [1024,128,128]
  const float* Wk = (const float*)d_in[1];      // [128,2048]
  const float* Wr = (const float*)d_in[2];      // [512,2048]
  const float* bias = (const float*)d_in[3];    // [2048]
  const float* Wd = (const float*)d_in[4];      // [512,128]
  const float* bd = (const float*)d_in[5];      // [128]
  float* out = (float*)d_out;                   // [1024, S, 128]
  const int S = out_size / (1024 * 128);        // 96

  char* w = (char*)d_ws;
  short* WT2     = (short*)w; w += (size_t)2048 * 1280 * 2;  // 5.24 MB
  short* WdecAll = (short*)w; w += (size_t)2176 * 1024 * 2;  // 4.46 MB
  float* bdecA   = (float*)w; w += (size_t)2176 * 4;
  short* AW0 = (short*)w; w += (size_t)1024 * 1280 * 2;      // 2.62 MB
  short* AW1 = (short*)w; w += (size_t)1024 * 1280 * 2;      // 2.62 MB
  short* AD0 = (short*)w; w += (size_t)1024 * 1024 * 2;      // 2.10 MB
  short* AD1 = (short*)w; w += (size_t)1024 * 1024 * 2;      // 2.10 MB
  float* Cst = (float*)w; w += (size_t)1024 * 512 * 4;       // 2.10 MB
  if ((size_t)(w - (char*)d_ws) > ws_size) return;           // clean fail

  hipMemsetAsync(AW0, 0, (size_t)1024 * 1280 * 2, stream);
  hipMemsetAsync(Cst, 0, (size_t)1024 * 512 * 4, stream);

  prep_w2<<<dim3(10, 32), 256, 0, stream>>>(Wk, Wr, WT2);
  wdec_split<<<dim3(8, 512), 256, 0, stream>>>(Wd, Wk, Wr, WdecAll);
  wd_append<<<256, 256, 0, stream>>>(Wd, WdecAll);
  bdec_all<<<9, 256, 0, stream>>>(bd, Wk, bias, bdecA);
  x0_init<<<64, 256, 0, stream>>>(inputs, AW0);

  short* AW[2] = { AW0, AW1 };
  short* AD[2] = { AD0, AD1 };

  // warmup: steps 0..126 -> AW ping-pong; step 127 -> AD0 ([h_hi|h_lo], stride 1024)
  for (int t = 0; t < 127; ++t) {
    lstm_step<0><<<512, 256, 0, stream>>>(
        AW[t & 1], AW[(t + 1) & 1], 1280, 128, 768,
        inputs + (size_t)(t + 1) * 128, Cst, WT2, bias, nullptr, 0, S);
  }
  lstm_step<0><<<512, 256, 0, stream>>>(
      AW[1], AD[0], 1024, 0, 512, nullptr, Cst, WT2, bias, nullptr, 0, S);

  // decode: step s computes h_s (512 gate blocks) and out[:,s-1,:] (16 proj blocks)
  for (int s = 1; s < S; ++s) {
    lstm_step<1><<<528, 256, 0, stream>>>(
        AD[(s + 1) & 1], AD[s & 1], 1024, 0, 512, nullptr, Cst,
        WdecAll, bdecA, out, s - 1, S);
  }
  // final projection of h_{S-1}
  lstm_step<2><<<16, 256, 0, stream>>>(
      AD[(S - 1) & 1], nullptr, 0, 0, 0, nullptr, Cst,
      WdecAll, bdecA, out, S - 1, S);
}

// Round 11
// 2634.506 us; speedup vs baseline: 2.7095x; 1.3714x over previous
//
#include <hip/hip_runtime.h>
#include <hip/hip_bf16.h>

typedef float f32x4 __attribute__((ext_vector_type(4)));
typedef short s16x8 __attribute__((ext_vector_type(8)));
typedef float floatx4 __attribute__((ext_vector_type(4)));

#define DEV static __device__ __forceinline__
#define WAITVM(N) asm volatile("s_waitcnt vmcnt(" #N ")" ::: "memory")

DEV void barrier_pipe() {
  __builtin_amdgcn_sched_barrier(0);
  __builtin_amdgcn_s_barrier();
  __builtin_amdgcn_sched_barrier(0);
}

DEV void gld_lds16(const void* g, void* l) {
  __builtin_amdgcn_global_load_lds(
      (const __attribute__((address_space(1))) void*)g,
      (__attribute__((address_space(3))) void*)l, 16, 0, 0);
}

DEV short f2bf(float x) {
  union { __hip_bfloat16 h; short s; } u;
  u.h = __float2bfloat16(x);
  return u.s;
}

DEV float bf2f(short s) {
  union { unsigned u; float f; } v;
  v.u = ((unsigned)(unsigned short)s) << 16;
  return v.f;
}

DEV void split2(float x, short& hi, short& lo) {
  hi = f2bf(x);
  lo = f2bf(x - bf2f(hi));
}

DEV float sigf(float x) {
  return 1.0f / (1.0f + exp2f(x * -1.44269504f));
}

DEV float tanhf2(float x) {
  float e = exp2f(fmaxf(x, -18.0f) * -2.88539008f);
  return (1.0f - e) / (1.0f + e);
}

DEV void mfma16(f32x4& d, s16x8 a, s16x8 b) {
  asm("v_mfma_f32_16x16x32_bf16 %0, %1, %2, %0" : "+v"(d) : "v"(a), "v"(b));
}

// ---- warm weights WT2[n][1280]: [Wk_hi(128)|Wr_hi(512)|Wk_lo(128)|Wr_lo(512)] ----
__global__ __launch_bounds__(256)
void prep_w2(const float* __restrict__ Wk, const float* __restrict__ Wr,
             short* __restrict__ WT2) {
  __shared__ float t[64 * 65];
  const int k0 = blockIdx.x * 64, n0 = blockIdx.y * 64;
  const int c = threadIdx.x & 63, r4 = threadIdx.x >> 6;
#pragma unroll
  for (int i = 0; i < 16; ++i) {
    int r = r4 * 16 + i;
    int k = k0 + r, n = n0 + c;
    t[r * 65 + c] = (k < 128) ? Wk[(size_t)k * 2048 + n] : Wr[(size_t)(k - 128) * 2048 + n];
  }
  __syncthreads();
#pragma unroll
  for (int i = 0; i < 16; ++i) {
    int nn = r4 * 16 + i;
    float v = t[c * 65 + nn];
    short hi, lo; split2(v, hi, lo);
    WT2[(size_t)(n0 + nn) * 1280 + k0 + c] = hi;
    WT2[(size_t)(n0 + nn) * 1280 + 640 + k0 + c] = lo;
  }
}

// ---- WdecAll rows 0..2047: Wdec = Wr + Wd@Wk (f32), [hi(512)|lo(512)] ----
__global__ __launch_bounds__(256)
void wdec_split(const float* __restrict__ Wd, const float* __restrict__ Wk,
                const float* __restrict__ Wr, short* __restrict__ WdecAll) {
  const int n = blockIdx.x * 256 + threadIdx.x;  // 0..2047
  const int kp = blockIdx.y;                     // 0..511
  float acc = Wr[(size_t)kp * 2048 + n];
#pragma unroll 8
  for (int j = 0; j < 128; ++j)
    acc = fmaf(Wd[(size_t)kp * 128 + j], Wk[(size_t)j * 2048 + n], acc);
  short hi, lo; split2(acc, hi, lo);
  WdecAll[(size_t)n * 1024 + kp] = hi;
  WdecAll[(size_t)n * 1024 + 512 + kp] = lo;
}

// ---- WdecAll rows 2048..2175: Wd columns ----
__global__ __launch_bounds__(256)
void wd_append(const float* __restrict__ Wd, short* __restrict__ WdecAll) {
  const int t = blockIdx.x * 256 + threadIdx.x;  // 0..65535
  const int k = t >> 7, n = t & 127;
  float v = Wd[(size_t)k * 128 + n];
  short hi, lo; split2(v, hi, lo);
  WdecAll[(size_t)(2048 + n) * 1024 + k] = hi;
  WdecAll[(size_t)(2048 + n) * 1024 + 512 + k] = lo;
}

// ---- bdecAll[0..2047] = b + bd@Wk ; [2048..2175] = bd ----
__global__ __launch_bounds__(256)
void bdec_all(const float* __restrict__ bd, const float* __restrict__ Wk,
              const float* __restrict__ b, float* __restrict__ bdecAll) {
  const int n = blockIdx.x * 256 + threadIdx.x;
  if (n < 2048) {
    float acc = b[n];
#pragma unroll 8
    for (int j = 0; j < 128; ++j) acc = fmaf(bd[j], Wk[(size_t)j * 2048 + n], acc);
    bdecAll[n] = acc;
  } else if (n < 2176) {
    bdecAll[n] = bd[n - 2048];
  }
}

// ---- x0 init: inputs[:,0,:] -> AW0 cols [0..128)=hi, [640..768)=lo ----
__global__ __launch_bounds__(256)
void x0_init(const float* __restrict__ inputs, short* __restrict__ AW0) {
  const int t = blockIdx.x * 256 + threadIdx.x;  // 16384
  const int r = t >> 4, c0 = (t & 15) * 8;
  const float* src = inputs + (size_t)r * 16384 + c0;
  floatx4 a = *(const floatx4*)src;
  floatx4 b = *(const floatx4*)(src + 4);
  s16x8 vh, vl;
#pragma unroll
  for (int e = 0; e < 8; ++e) {
    float x = (e < 4) ? a[e] : b[e - 4];
    short hi, lo; split2(x, hi, lo);
    vh[e] = hi; vl[e] = lo;
  }
  *(s16x8*)(AW0 + (size_t)r * 1280 + c0) = vh;
  *(s16x8*)(AW0 + (size_t)r * 1280 + 640 + c0) = vl;
}

// ---------------- LSTM step: 64m x 32u tile, 512 threads (8 waves), grid 256 ----------------
// MODE 0 (warm):  A=AW (stride 1280), W=WT2, NKT=20. 3 loads/thread/stage.
// MODE 1 (decode):A=AD (stride 1024), W=WdecAll, NKT=16. +Bp ring (16 proj rows,
//                 padded to 64, 1 load/thread); wu2==0 waves add proj tile
//                 (16m x 16n, 8 n valid) -> out[:,sidx,:]. 4 loads/thread/stage.
// MODE 2 (final proj): grid 16, B rows 2048+, each wave 16m x 64n. 3 loads/thread.
// Waves: wid 0..7 = (wm2 = wid&3 -> 16 m rows, wu2 = wid>>2 -> 16 u cols).
// 3-ring LDS: A 3x8KB @0; B 3x16KB @24576; Bp 3x8KB @73728 (MODE 1 only).
template <int MODE>
__global__ __launch_bounds__(512)
void lstm_step(const short* __restrict__ Ain, short* __restrict__ hout,
               int hstride, int hioff, int looff,
               const float* __restrict__ xnext,
               float* __restrict__ Cst,
               const short* __restrict__ W2,
               const float* __restrict__ bias,
               float* __restrict__ out, int sidx, int S) {
  constexpr int NKT  = (MODE == 0) ? 20 : 16;
  constexpr int ASTR = (MODE == 0) ? 1280 : 1024;  // A row stride == W row stride
  constexpr int LDSZ = (MODE == 1) ? 98304 : 73728;
  __shared__ char lds[LDSZ];
  const int tid = threadIdx.x, lane = tid & 63, wid = tid >> 6;
  const int l15 = lane & 15, l4 = lane >> 4;
  const int wm2 = wid & 3, wu2 = wid >> 2;
  const int bid = blockIdx.x;
  int m0, u0, strip;
  if (MODE == 2) {
    m0 = bid * 64; u0 = 0; strip = 0;
  } else {
    const int jb = bid >> 3;
    strip = (bid & 7) + ((jb >> 4) << 3);  // XCD-local strips
    m0 = (jb & 15) * 64;
    u0 = strip * 32;
  }
  const int wbase = wid * 1024;

  auto stage = [&](int kt, int bsel) {
    char* B = lds + 24576 + bsel * 16384;
#pragma unroll
    for (int p = 0; p < 2; ++p) {
      int idx = p * 512 + tid;
      int r = idx >> 3, jp = idx & 7;
      int j = jp ^ (r & 7);
      int gu = (MODE == 2) ? (2048 + r) : (((r >> 5) << 9) + u0 + (r & 31));
      gld_lds16(W2 + (size_t)gu * ASTR + kt * 64 + j * 8, B + p * 8192 + wbase);
    }
    char* A = lds + bsel * 8192;
    {
      int r = tid >> 3;
      int j = (tid & 7) ^ (r & 7);
      gld_lds16(Ain + (size_t)(m0 + r) * ASTR + kt * 64 + j * 8, A + wbase);
    }
    if (MODE == 1) {
      char* Bp = lds + 73728 + bsel * 8192;
      int r = tid >> 3;                 // 0..63, real rows = r & 15 (4x duplicated)
      int j = (tid & 7) ^ (r & 7);
      gld_lds16(W2 + (size_t)(2048 + strip * 8 + (r & 15)) * 1024 + kt * 64 + j * 8,
                Bp + wbase);
    }
  };

  f32x4 acc[4] = {};
  f32x4 accp = {};
  stage(0, 0);
  stage(1, 1);
#pragma unroll
  for (int kt = 0; kt < NKT; ++kt) {
    if (kt == NKT - 1) { WAITVM(0); }
    else if (MODE == 1) { WAITVM(4); }
    else { WAITVM(3); }
    barrier_pipe();
    if (kt + 2 < NKT) stage(kt + 2, (kt + 2) % 3);
    const char* A = lds + (kt % 3) * 8192;
    const char* B = lds + 24576 + (kt % 3) * 16384;
    const char* Bp = lds + 73728 + (kt % 3) * 8192;
#pragma unroll
    for (int s2 = 0; s2 < 2; ++s2) {
      const int jd = s2 * 4 + l4;
      const int r = wm2 * 16 + l15;
      s16x8 av = *(const s16x8*)(A + r * 128 + ((jd ^ (r & 7)) << 4));
      if (MODE == 2) {
#pragma unroll
        for (int nt = 0; nt < 4; ++nt) {
          const int rB = wu2 * 64 + nt * 16 + l15;
          s16x8 bv = *(const s16x8*)(B + rB * 128 + ((jd ^ (rB & 7)) << 4));
          mfma16(acc[nt], av, bv);
        }
      } else {
#pragma unroll
        for (int g = 0; g < 4; ++g) {
          const int rB = g * 32 + wu2 * 16 + l15;
          s16x8 bv = *(const s16x8*)(B + rB * 128 + ((jd ^ (rB & 7)) << 4));
          mfma16(acc[g], av, bv);
        }
        if (MODE == 1 && wu2 == 0) {
          const int rp = l15;
          s16x8 bvp = *(const s16x8*)(Bp + rp * 128 + ((jd ^ (rp & 7)) << 4));
          mfma16(accp, av, bvp);
        }
      }
    }
  }

  asm volatile("s_nop 7\ns_nop 7\ns_nop 7");

  if (MODE == 2) {
#pragma unroll
    for (int nt = 0; nt < 4; ++nt) {
      const int n = wu2 * 64 + nt * 16 + l15;
      const float bb = bias[2048 + n];
#pragma unroll
      for (int rr = 0; rr < 4; ++rr) {
        const int m = m0 + wm2 * 16 + (l4 << 2) + rr;
        out[(size_t)m * ((size_t)S * 128) + (size_t)sidx * 128 + n] = acc[nt][rr] + bb;
      }
    }
    return;
  }

  // gate epilogue
  const int u = u0 + wu2 * 16 + l15;
  const float bi = bias[u], bf_ = bias[512 + u], bg = bias[1024 + u], bo = bias[1536 + u];
#pragma unroll
  for (int rr = 0; rr < 4; ++rr) {
    const int m = m0 + wm2 * 16 + (l4 << 2) + rr;
    const size_t off = (size_t)m * 512 + u;
    float ig = sigf(acc[0][rr] + bi);
    float fg = sigf(acc[1][rr] + bf_);
    float gg = tanhf2(acc[2][rr] + bg);
    float og = sigf(acc[3][rr] + bo);
    float cn = fg * Cst[off] + ig * gg;
    Cst[off] = cn;
    float hv = og * tanhf2(cn);
    short hh, hl; split2(hv, hh, hl);
    hout[(size_t)m * hstride + hioff + u] = hh;
    hout[(size_t)m * hstride + looff + u] = hl;
  }

  // fused projection store (decode): block (mblk,strip) -> rows m0.., cols strip*8..+8
  if (MODE == 1 && wu2 == 0 && l15 < 8) {
    const int n = strip * 8 + l15;
    const float bb = bias[2048 + n];
#pragma unroll
    for (int rr = 0; rr < 4; ++rr) {
      const int m = m0 + wm2 * 16 + (l4 << 2) + rr;
      out[(size_t)m * ((size_t)S * 128) + (size_t)sidx * 128 + n] = accp[rr] + bb;
    }
  }

  // next-x conversion (warmup only; strip-0 blocks cover their 64 m rows)
  if (MODE == 0 && xnext != nullptr && strip == 0) {
    const int r = tid >> 3;
    const int c0 = (tid & 7) * 16;
    const float* src = xnext + (size_t)(m0 + r) * 16384 + c0;
    short* dst = hout + (size_t)(m0 + r) * 1280;
#pragma unroll
    for (int j = 0; j < 16; j += 8) {
      floatx4 a = *(const floatx4*)(src + j);
      floatx4 b = *(const floatx4*)(src + j + 4);
      s16x8 vh, vl;
#pragma unroll
      for (int e = 0; e < 8; ++e) {
        float x = (e < 4) ? a[e] : b[e - 4];
        short hi, lo; split2(x, hi, lo);
        vh[e] = hi; vl[e] = lo;
      }
      *(s16x8*)(dst + c0 + j) = vh;
      *(s16x8*)(dst + 640 + c0 + j) = vl;
    }
  }
}

extern "C" void kernel_launch(void* const* d_in, const int* in_sizes, int n_in,
                              void* d_out, int out_size, void* d_ws, size_t ws_size,
                              hipStream_t stream) {
  const float* inputs = (const float*)d_in[0];  // [1024,128,128]
  const float* Wk = (const float*)d_in[1];      // [128,2048]
  const float* Wr = (const float*)d_in[2];      // [512,2048]
  const float* bias = (const float*)d_in[3];    // [2048]
  const float* Wd = (const float*)d_in[4];      // [512,128]
  const float* bd = (const float*)d_in[5];      // [128]
  float* out = (float*)d_out;                   // [1024, S, 128]
  const int S = out_size / (1024 * 128);        // 96

  char* w = (char*)d_ws;
  short* WT2     = (short*)w; w += (size_t)2048 * 1280 * 2;  // 5.24 MB
  short* WdecAll = (short*)w; w += (size_t)2208 * 1024 * 2;  // 4.52 MB (rows 2176..2207 pad)
  float* bdecA   = (float*)w; w += (size_t)2176 * 4;
  short* AW0 = (short*)w; w += (size_t)1024 * 1280 * 2;      // 2.62 MB
  short* AW1 = (short*)w; w += (size_t)1024 * 1280 * 2;      // 2.62 MB
  short* AD0 = (short*)w; w += (size_t)1024 * 1024 * 2;      // 2.10 MB
  short* AD1 = (short*)w; w += (size_t)1024 * 1024 * 2;      // 2.10 MB
  float* Cst = (float*)w; w += (size_t)1024 * 512 * 4;       // 2.10 MB
  if ((size_t)(w - (char*)d_ws) > ws_size) return;           // clean fail

  hipMemsetAsync(AW0, 0, (size_t)1024 * 1280 * 2, stream);
  hipMemsetAsync(Cst, 0, (size_t)1024 * 512 * 4, stream);

  prep_w2<<<dim3(10, 32), 256, 0, stream>>>(Wk, Wr, WT2);
  wdec_split<<<dim3(8, 512), 256, 0, stream>>>(Wd, Wk, Wr, WdecAll);
  wd_append<<<256, 256, 0, stream>>>(Wd, WdecAll);
  bdec_all<<<9, 256, 0, stream>>>(bd, Wk, bias, bdecA);
  x0_init<<<64, 256, 0, stream>>>(inputs, AW0);

  short* AW[2] = { AW0, AW1 };
  short* AD[2] = { AD0, AD1 };

  // warmup: steps 0..126 -> AW ping-pong; step 127 -> AD0 ([h_hi|h_lo], stride 1024)
  for (int t = 0; t < 127; ++t) {
    lstm_step<0><<<256, 512, 0, stream>>>(
        AW[t & 1], AW[(t + 1) & 1], 1280, 128, 768,
        inputs + (size_t)(t + 1) * 128, Cst, WT2, bias, nullptr, 0, S);
  }
  lstm_step<0><<<256, 512, 0, stream>>>(
      AW[1], AD[0], 1024, 0, 512, nullptr, Cst, WT2, bias, nullptr, 0, S);

  // decode: step s computes h_s (gates) and out[:,s-1,:] (fused proj of h_{s-1})
  for (int s = 1; s < S; ++s) {
    lstm_step<1><<<256, 512, 0, stream>>>(
        AD[(s + 1) & 1], AD[s & 1], 1024, 0, 512, nullptr, Cst,
        WdecAll, bdecA, out, s - 1, S);
  }
  // final projection of h_{S-1}
  lstm_step<2><<<16, 512, 0, stream>>>(
      AD[(S - 1) & 1], nullptr, 0, 0, 0, nullptr, Cst,
      WdecAll, bdecA, out, S - 1, S);
}

// Round 12
// 2627.027 us; speedup vs baseline: 2.7173x; 1.0028x over previous
//
#include <hip/hip_runtime.h>
#include <hip/hip_bf16.h>

typedef float f32x4 __attribute__((ext_vector_type(4)));
typedef short s16x8 __attribute__((ext_vector_type(8)));
typedef float floatx4 __attribute__((ext_vector_type(4)));

#define DEV static __device__ __forceinline__
#define WAITVM(N) asm volatile("s_waitcnt vmcnt(" #N ")" ::: "memory")

DEV void barrier_pipe() {
  __builtin_amdgcn_sched_barrier(0);
  __builtin_amdgcn_s_barrier();
  __builtin_amdgcn_sched_barrier(0);
}

DEV void gld_lds16(const void* g, void* l) {
  __builtin_amdgcn_global_load_lds(
      (const __attribute__((address_space(1))) void*)g,
      (__attribute__((address_space(3))) void*)l, 16, 0, 0);
}

DEV short f2bf(float x) {
  union { __hip_bfloat16 h; short s; } u;
  u.h = __float2bfloat16(x);
  return u.s;
}

DEV float bf2f(short s) {
  union { unsigned u; float f; } v;
  v.u = ((unsigned)(unsigned short)s) << 16;
  return v.f;
}

DEV void split2(float x, short& hi, short& lo) {
  hi = f2bf(x);
  lo = f2bf(x - bf2f(hi));
}

DEV float sigf(float x) {
  return 1.0f / (1.0f + exp2f(x * -1.44269504f));
}

DEV float tanhf2(float x) {
  float e = exp2f(fmaxf(x, -18.0f) * -2.88539008f);
  return (1.0f - e) / (1.0f + e);
}

DEV void mfma16(f32x4& d, s16x8 a, s16x8 b) {
  asm("v_mfma_f32_16x16x32_bf16 %0, %1, %2, %0" : "+v"(d) : "v"(a), "v"(b));
}

// ---- warm weights WT2[n][1280]: [Wk_hi(128)|Wr_hi(512)|Wk_lo(128)|Wr_lo(512)] ----
__global__ __launch_bounds__(256)
void prep_w2(const float* __restrict__ Wk, const float* __restrict__ Wr,
             short* __restrict__ WT2) {
  __shared__ float t[64 * 65];
  const int k0 = blockIdx.x * 64, n0 = blockIdx.y * 64;
  const int c = threadIdx.x & 63, r4 = threadIdx.x >> 6;
#pragma unroll
  for (int i = 0; i < 16; ++i) {
    int r = r4 * 16 + i;
    int k = k0 + r, n = n0 + c;
    t[r * 65 + c] = (k < 128) ? Wk[(size_t)k * 2048 + n] : Wr[(size_t)(k - 128) * 2048 + n];
  }
  __syncthreads();
#pragma unroll
  for (int i = 0; i < 16; ++i) {
    int nn = r4 * 16 + i;
    float v = t[c * 65 + nn];
    short hi, lo; split2(v, hi, lo);
    WT2[(size_t)(n0 + nn) * 1280 + k0 + c] = hi;
    WT2[(size_t)(n0 + nn) * 1280 + 640 + k0 + c] = lo;
  }
}

// ---- WdecAll rows 0..2047: Wdec = Wr + Wd@Wk (f32), [hi(512)|lo(512)] ----
__global__ __launch_bounds__(256)
void wdec_split(const float* __restrict__ Wd, const float* __restrict__ Wk,
                const float* __restrict__ Wr, short* __restrict__ WdecAll) {
  const int n = blockIdx.x * 256 + threadIdx.x;  // 0..2047
  const int kp = blockIdx.y;                     // 0..511
  float acc = Wr[(size_t)kp * 2048 + n];
#pragma unroll 8
  for (int j = 0; j < 128; ++j)
    acc = fmaf(Wd[(size_t)kp * 128 + j], Wk[(size_t)j * 2048 + n], acc);
  short hi, lo; split2(acc, hi, lo);
  WdecAll[(size_t)n * 1024 + kp] = hi;
  WdecAll[(size_t)n * 1024 + 512 + kp] = lo;
}

// ---- WdecAll rows 2048..2175: Wd columns ----
__global__ __launch_bounds__(256)
void wd_append(const float* __restrict__ Wd, short* __restrict__ WdecAll) {
  const int t = blockIdx.x * 256 + threadIdx.x;  // 0..65535
  const int k = t >> 7, n = t & 127;
  float v = Wd[(size_t)k * 128 + n];
  short hi, lo; split2(v, hi, lo);
  WdecAll[(size_t)(2048 + n) * 1024 + k] = hi;
  WdecAll[(size_t)(2048 + n) * 1024 + 512 + k] = lo;
}

// ---- bdecAll[0..2047] = b + bd@Wk ; [2048..2175] = bd ----
__global__ __launch_bounds__(256)
void bdec_all(const float* __restrict__ bd, const float* __restrict__ Wk,
              const float* __restrict__ b, float* __restrict__ bdecAll) {
  const int n = blockIdx.x * 256 + threadIdx.x;
  if (n < 2048) {
    float acc = b[n];
#pragma unroll 8
    for (int j = 0; j < 128; ++j) acc = fmaf(bd[j], Wk[(size_t)j * 2048 + n], acc);
    bdecAll[n] = acc;
  } else if (n < 2176) {
    bdecAll[n] = bd[n - 2048];
  }
}

// ---- x0 init: inputs[:,0,:] -> AW0 cols [0..128)=hi, [640..768)=lo ----
__global__ __launch_bounds__(256)
void x0_init(const float* __restrict__ inputs, short* __restrict__ AW0) {
  const int t = blockIdx.x * 256 + threadIdx.x;  // 16384
  const int r = t >> 4, c0 = (t & 15) * 8;
  const float* src = inputs + (size_t)r * 16384 + c0;
  floatx4 a = *(const floatx4*)src;
  floatx4 b = *(const floatx4*)(src + 4);
  s16x8 vh, vl;
#pragma unroll
  for (int e = 0; e < 8; ++e) {
    float x = (e < 4) ? a[e] : b[e - 4];
    short hi, lo; split2(x, hi, lo);
    vh[e] = hi; vl[e] = lo;
  }
  *(s16x8*)(AW0 + (size_t)r * 1280 + c0) = vh;
  *(s16x8*)(AW0 + (size_t)r * 1280 + 640 + c0) = vl;
}

// ---------------- LSTM step: 64m x 32u tile, 512 threads (8 waves), grid 256 ----------------
// MODE 0 (warm):  ring-4/prefetch-3. A=AW (stride 1280), W=WT2, NKT=20. 3 loads/thr/stage.
// MODE 1 (decode):ring-3/prefetch-2 (round-11-proven). A=AD (1024), W=WdecAll, NKT=16.
//                 +Bp ring; wu2==0 waves add proj tile -> out[:,sidx,:]. 4 loads/thr/stage.
// MODE 2 (final proj): ring-4. grid 16, B rows 2048+, each wave 16m x 64n.
// s_setprio(1) around the MFMA cluster (T5).
// LDS: MODE 1: A 3x8K @0, B 3x16K @24576, Bp 3x8K @73728 (96K alloc).
//      else:   A 4x8K @0, B 4x16K @32768 (96K).
template <int MODE>
__global__ __launch_bounds__(512)
void lstm_step(const short* __restrict__ Ain, short* __restrict__ hout,
               int hstride, int hioff, int looff,
               const float* __restrict__ xnext,
               float* __restrict__ Cst,
               const short* __restrict__ W2,
               const float* __restrict__ bias,
               float* __restrict__ out, int sidx, int S) {
  constexpr int NKT  = (MODE == 0) ? 20 : 16;
  constexpr int ASTR = (MODE == 0) ? 1280 : 1024;  // A row stride == W row stride
  constexpr int RING = (MODE == 1) ? 3 : 4;
  constexpr int BOFF = (MODE == 1) ? 24576 : 32768;
  __shared__ char lds[98304];
  const int tid = threadIdx.x, lane = tid & 63, wid = tid >> 6;
  const int l15 = lane & 15, l4 = lane >> 4;
  const int wm2 = wid & 3, wu2 = wid >> 2;
  const int bid = blockIdx.x;
  int m0, u0, strip;
  if (MODE == 2) {
    m0 = bid * 64; u0 = 0; strip = 0;
  } else {
    const int jb = bid >> 3;
    strip = (bid & 7) + ((jb >> 4) << 3);  // XCD-local strips
    m0 = (jb & 15) * 64;
    u0 = strip * 32;
  }
  const int wbase = wid * 1024;

  auto stage = [&](int kt, int bsel) {
    char* B = lds + BOFF + bsel * 16384;
#pragma unroll
    for (int p = 0; p < 2; ++p) {
      int idx = p * 512 + tid;
      int r = idx >> 3, jp = idx & 7;
      int j = jp ^ (r & 7);
      int gu = (MODE == 2) ? (2048 + r) : (((r >> 5) << 9) + u0 + (r & 31));
      gld_lds16(W2 + (size_t)gu * ASTR + kt * 64 + j * 8, B + p * 8192 + wbase);
    }
    char* A = lds + bsel * 8192;
    {
      int r = tid >> 3;
      int j = (tid & 7) ^ (r & 7);
      gld_lds16(Ain + (size_t)(m0 + r) * ASTR + kt * 64 + j * 8, A + wbase);
    }
    if (MODE == 1) {
      char* Bp = lds + 73728 + bsel * 8192;
      int r = tid >> 3;                 // 0..63, real rows = r & 15 (4x duplicated)
      int j = (tid & 7) ^ (r & 7);
      gld_lds16(W2 + (size_t)(2048 + strip * 8 + (r & 15)) * 1024 + kt * 64 + j * 8,
                Bp + wbase);
    }
  };

  f32x4 acc[4] = {};
  f32x4 accp = {};
  stage(0, 0);
  stage(1, 1);
  if (RING == 4) stage(2, 2);
#pragma unroll
  for (int kt = 0; kt < NKT; ++kt) {
    // block-uniform counted vmcnt: stage(kt) must be complete.
    if (MODE == 1) {
      if (kt < NKT - 1) { WAITVM(4); } else { WAITVM(0); }
    } else {
      if (kt < NKT - 2) { WAITVM(6); }
      else if (kt == NKT - 2) { WAITVM(3); }
      else { WAITVM(0); }
    }
    barrier_pipe();
    if (kt + RING - 1 < NKT) stage(kt + RING - 1, (kt + RING - 1) % RING);
    const char* A = lds + (kt % RING) * 8192;
    const char* B = lds + BOFF + (kt % RING) * 16384;
    const char* Bp = lds + 73728 + (kt % 3) * 8192;
    __builtin_amdgcn_s_setprio(1);
#pragma unroll
    for (int s2 = 0; s2 < 2; ++s2) {
      const int jd = s2 * 4 + l4;
      const int r = wm2 * 16 + l15;
      s16x8 av = *(const s16x8*)(A + r * 128 + ((jd ^ (r & 7)) << 4));
      if (MODE == 2) {
#pragma unroll
        for (int nt = 0; nt < 4; ++nt) {
          const int rB = wu2 * 64 + nt * 16 + l15;
          s16x8 bv = *(const s16x8*)(B + rB * 128 + ((jd ^ (rB & 7)) << 4));
          mfma16(acc[nt], av, bv);
        }
      } else {
#pragma unroll
        for (int g = 0; g < 4; ++g) {
          const int rB = g * 32 + wu2 * 16 + l15;
          s16x8 bv = *(const s16x8*)(B + rB * 128 + ((jd ^ (rB & 7)) << 4));
          mfma16(acc[g], av, bv);
        }
        if (MODE == 1 && wu2 == 0) {
          const int rp = l15;
          s16x8 bvp = *(const s16x8*)(Bp + rp * 128 + ((jd ^ (rp & 7)) << 4));
          mfma16(accp, av, bvp);
        }
      }
    }
    __builtin_amdgcn_s_setprio(0);
  }

  asm volatile("s_nop 7\ns_nop 7\ns_nop 7");

  if (MODE == 2) {
#pragma unroll
    for (int nt = 0; nt < 4; ++nt) {
      const int n = wu2 * 64 + nt * 16 + l15;
      const float bb = bias[2048 + n];
#pragma unroll
      for (int rr = 0; rr < 4; ++rr) {
        const int m = m0 + wm2 * 16 + (l4 << 2) + rr;
        out[(size_t)m * ((size_t)S * 128) + (size_t)sidx * 128 + n] = acc[nt][rr] + bb;
      }
    }
    return;
  }

  // gate epilogue
  const int u = u0 + wu2 * 16 + l15;
  const float bi = bias[u], bf_ = bias[512 + u], bg = bias[1024 + u], bo = bias[1536 + u];
#pragma unroll
  for (int rr = 0; rr < 4; ++rr) {
    const int m = m0 + wm2 * 16 + (l4 << 2) + rr;
    const size_t off = (size_t)m * 512 + u;
    float ig = sigf(acc[0][rr] + bi);
    float fg = sigf(acc[1][rr] + bf_);
    float gg = tanhf2(acc[2][rr] + bg);
    float og = sigf(acc[3][rr] + bo);
    float cn = fg * Cst[off] + ig * gg;
    Cst[off] = cn;
    float hv = og * tanhf2(cn);
    short hh, hl; split2(hv, hh, hl);
    hout[(size_t)m * hstride + hioff + u] = hh;
    hout[(size_t)m * hstride + looff + u] = hl;
  }

  // fused projection store (decode): block (mblk,strip) -> rows m0.., cols strip*8..+8
  if (MODE == 1 && wu2 == 0 && l15 < 8) {
    const int n = strip * 8 + l15;
    const float bb = bias[2048 + n];
#pragma unroll
    for (int rr = 0; rr < 4; ++rr) {
      const int m = m0 + wm2 * 16 + (l4 << 2) + rr;
      out[(size_t)m * ((size_t)S * 128) + (size_t)sidx * 128 + n] = accp[rr] + bb;
    }
  }

  // next-x conversion (warmup only; strip-0 blocks cover their 64 m rows)
  if (MODE == 0 && xnext != nullptr && strip == 0) {
    const int r = tid >> 3;
    const int c0 = (tid & 7) * 16;
    const float* src = xnext + (size_t)(m0 + r) * 16384 + c0;
    short* dst = hout + (size_t)(m0 + r) * 1280;
#pragma unroll
    for (int j = 0; j < 16; j += 8) {
      floatx4 a = *(const floatx4*)(src + j);
      floatx4 b = *(const floatx4*)(src + j + 4);
      s16x8 vh, vl;
#pragma unroll
      for (int e = 0; e < 8; ++e) {
        float x = (e < 4) ? a[e] : b[e - 4];
        short hi, lo; split2(x, hi, lo);
        vh[e] = hi; vl[e] = lo;
      }
      *(s16x8*)(dst + c0 + j) = vh;
      *(s16x8*)(dst + 640 + c0 + j) = vl;
    }
  }
}

extern "C" void kernel_launch(void* const* d_in, const int* in_sizes, int n_in,
                              void* d_out, int out_size, void* d_ws, size_t ws_size,
                              hipStream_t stream) {
  const float* inputs = (const float*)d_in[0];  // [1024,128,128]
  const float* Wk = (const float*)d_in[1];      // [128,2048]
  const float* Wr = (const float*)d_in[2];      // [512,2048]
  const float* bias = (const float*)d_in[3];    // [2048]
  const float* Wd = (const float*)d_in[4];      // [512,128]
  const float* bd = (const float*)d_in[5];      // [128]
  float* out = (float*)d_out;                   // [1024, S, 128]
  const int S = out_size / (1024 * 128);        // 96

  char* w = (char*)d_ws;
  short* WT2     = (short*)w; w += (size_t)2048 * 1280 * 2;  // 5.24 MB
  short* WdecAll = (short*)w; w += (size_t)2208 * 1024 * 2;  // 4.52 MB (rows 2176..2207 pad)
  float* bdecA   = (float*)w; w += (size_t)2176 * 4;
  short* AW0 = (short*)w; w += (size_t)1024 * 1280 * 2;      // 2.62 MB
  short* AW1 = (short*)w; w += (size_t)1024 * 1280 * 2;      // 2.62 MB
  short* AD0 = (short*)w; w += (size_t)1024 * 1024 * 2;      // 2.10 MB
  short* AD1 = (short*)w; w += (size_t)1024 * 1024 * 2;      // 2.10 MB
  float* Cst = (float*)w; w += (size_t)1024 * 512 * 4;       // 2.10 MB
  if ((size_t)(w - (char*)d_ws) > ws_size) return;           // clean fail

  hipMemsetAsync(AW0, 0, (size_t)1024 * 1280 * 2, stream);
  hipMemsetAsync(Cst, 0, (size_t)1024 * 512 * 4, stream);

  prep_w2<<<dim3(10, 32), 256, 0, stream>>>(Wk, Wr, WT2);
  wdec_split<<<dim3(8, 512), 256, 0, stream>>>(Wd, Wk, Wr, WdecAll);
  wd_append<<<256, 256, 0, stream>>>(Wd, WdecAll);
  bdec_all<<<9, 256, 0, stream>>>(bd, Wk, bias, bdecA);
  x0_init<<<64, 256, 0, stream>>>(inputs, AW0);

  short* AW[2] = { AW0, AW1 };
  short* AD[2] = { AD0, AD1 };

  // warmup: steps 0..126 -> AW ping-pong; step 127 -> AD0 ([h_hi|h_lo], stride 1024)
  for (int t = 0; t < 127; ++t) {
    lstm_step<0><<<256, 512, 0, stream>>>(
        AW[t & 1], AW[(t + 1) & 1], 1280, 128, 768,
        inputs + (size_t)(t + 1) * 128, Cst, WT2, bias, nullptr, 0, S);
  }
  lstm_step<0><<<256, 512, 0, stream>>>(
      AW[1], AD[0], 1024, 0, 512, nullptr, Cst, WT2, bias, nullptr, 0, S);

  // decode: step s computes h_s (gates) and out[:,s-1,:] (fused proj of h_{s-1})
  for (int s = 1; s < S; ++s) {
    lstm_step<1><<<256, 512, 0, stream>>>(
        AD[(s + 1) & 1], AD[s & 1], 1024, 0, 512, nullptr, Cst,
        WdecAll, bdecA, out, s - 1, S);
  }
  // final projection of h_{S-1}
  lstm_step<2><<<16, 512, 0, stream>>>(
      AD[(S - 1) & 1], nullptr, 0, 0, 0, nullptr, Cst,
      WdecAll, bdecA, out, S - 1, S);
}

// Round 13
// 2577.236 us; speedup vs baseline: 2.7697x; 1.0193x over previous
//
#include <hip/hip_runtime.h>
#include <hip/hip_bf16.h>

typedef float f32x4 __attribute__((ext_vector_type(4)));
typedef short s16x8 __attribute__((ext_vector_type(8)));
typedef float floatx4 __attribute__((ext_vector_type(4)));

#define DEV static __device__ __forceinline__
#define WAITVM(N) asm volatile("s_waitcnt vmcnt(" #N ")" ::: "memory")

DEV void barrier_pipe() {
  __builtin_amdgcn_sched_barrier(0);
  __builtin_amdgcn_s_barrier();
  __builtin_amdgcn_sched_barrier(0);
}

DEV void gld_lds16(const void* g, void* l) {
  __builtin_amdgcn_global_load_lds(
      (const __attribute__((address_space(1))) void*)g,
      (__attribute__((address_space(3))) void*)l, 16, 0, 0);
}

DEV short f2bf(float x) {
  union { __hip_bfloat16 h; short s; } u;
  u.h = __float2bfloat16(x);
  return u.s;
}

DEV float bf2f(short s) {
  union { unsigned u; float f; } v;
  v.u = ((unsigned)(unsigned short)s) << 16;
  return v.f;
}

DEV void split2(float x, short& hi, short& lo) {
  hi = f2bf(x);
  lo = f2bf(x - bf2f(hi));
}

DEV float sigf(float x) {
  return 1.0f / (1.0f + exp2f(x * -1.44269504f));
}

DEV float tanhf2(float x) {
  float e = exp2f(fmaxf(x, -18.0f) * -2.88539008f);
  return (1.0f - e) / (1.0f + e);
}

DEV void mfma16(f32x4& d, s16x8 a, s16x8 b) {
  asm("v_mfma_f32_16x16x32_bf16 %0, %1, %2, %0" : "+v"(d) : "v"(a), "v"(b));
}

// ---- warm weights WT2[n][1280]: [Wk_hi(128)|Wr_hi(512)|Wk_lo(128)|Wr_lo(512)] ----
__global__ __launch_bounds__(256)
void prep_w2(const float* __restrict__ Wk, const float* __restrict__ Wr,
             short* __restrict__ WT2) {
  __shared__ float t[64 * 65];
  const int k0 = blockIdx.x * 64, n0 = blockIdx.y * 64;
  const int c = threadIdx.x & 63, r4 = threadIdx.x >> 6;
#pragma unroll
  for (int i = 0; i < 16; ++i) {
    int r = r4 * 16 + i;
    int k = k0 + r, n = n0 + c;
    t[r * 65 + c] = (k < 128) ? Wk[(size_t)k * 2048 + n] : Wr[(size_t)(k - 128) * 2048 + n];
  }
  __syncthreads();
#pragma unroll
  for (int i = 0; i < 16; ++i) {
    int nn = r4 * 16 + i;
    float v = t[c * 65 + nn];
    short hi, lo; split2(v, hi, lo);
    WT2[(size_t)(n0 + nn) * 1280 + k0 + c] = hi;
    WT2[(size_t)(n0 + nn) * 1280 + 640 + k0 + c] = lo;
  }
}

// ---- WdecAll rows 0..2047: Wdec = Wr + Wd@Wk (f32), [hi(512)|lo(512)] ----
__global__ __launch_bounds__(256)
void wdec_split(const float* __restrict__ Wd, const float* __restrict__ Wk,
                const float* __restrict__ Wr, short* __restrict__ WdecAll) {
  const int n = blockIdx.x * 256 + threadIdx.x;  // 0..2047
  const int kp = blockIdx.y;                     // 0..511
  float acc = Wr[(size_t)kp * 2048 + n];
#pragma unroll 8
  for (int j = 0; j < 128; ++j)
    acc = fmaf(Wd[(size_t)kp * 128 + j], Wk[(size_t)j * 2048 + n], acc);
  short hi, lo; split2(acc, hi, lo);
  WdecAll[(size_t)n * 1024 + kp] = hi;
  WdecAll[(size_t)n * 1024 + 512 + kp] = lo;
}

// ---- WdecAll rows 2048..2175: Wd columns (+ zero pad rows 2176..2207) ----
__global__ __launch_bounds__(256)
void wd_append(const float* __restrict__ Wd, short* __restrict__ WdecAll) {
  const int t = blockIdx.x * 256 + threadIdx.x;  // 0..65535
  const int k = t >> 7, n = t & 127;
  float v = Wd[(size_t)k * 128 + n];
  short hi, lo; split2(v, hi, lo);
  WdecAll[(size_t)(2048 + n) * 1024 + k] = hi;
  WdecAll[(size_t)(2048 + n) * 1024 + 512 + k] = lo;
  if (n < 32) {  // zero the pad rows so preload reads are defined
    WdecAll[(size_t)(2176 + n) * 1024 + k] = 0;
    WdecAll[(size_t)(2176 + n) * 1024 + 512 + k] = 0;
  }
}

// ---- bdecAll[0..2047] = b + bd@Wk ; [2048..2175] = bd ----
__global__ __launch_bounds__(256)
void bdec_all(const float* __restrict__ bd, const float* __restrict__ Wk,
              const float* __restrict__ b, float* __restrict__ bdecAll) {
  const int n = blockIdx.x * 256 + threadIdx.x;
  if (n < 2048) {
    float acc = b[n];
#pragma unroll 8
    for (int j = 0; j < 128; ++j) acc = fmaf(bd[j], Wk[(size_t)j * 2048 + n], acc);
    bdecAll[n] = acc;
  } else if (n < 2176) {
    bdecAll[n] = bd[n - 2048];
  }
}

// ---- x0 init: inputs[:,0,:] -> AW0 cols [0..128)=hi, [640..768)=lo ----
__global__ __launch_bounds__(256)
void x0_init(const float* __restrict__ inputs, short* __restrict__ AW0) {
  const int t = blockIdx.x * 256 + threadIdx.x;  // 16384
  const int r = t >> 4, c0 = (t & 15) * 8;
  const float* src = inputs + (size_t)r * 16384 + c0;
  floatx4 a = *(const floatx4*)src;
  floatx4 b = *(const floatx4*)(src + 4);
  s16x8 vh, vl;
#pragma unroll
  for (int e = 0; e < 8; ++e) {
    float x = (e < 4) ? a[e] : b[e - 4];
    short hi, lo; split2(x, hi, lo);
    vh[e] = hi; vl[e] = lo;
  }
  *(s16x8*)(AW0 + (size_t)r * 1280 + c0) = vh;
  *(s16x8*)(AW0 + (size_t)r * 1280 + 640 + c0) = vl;
}

// ---------------- LSTM step: 64m x 32u tile, 512 threads (8 waves), grid 256 ----------------
// MODE 0 (warm):  ring-4/prefetch-3. A=AW (stride 1280), W=WT2, NKT=20. 3 loads/thr/stage.
// MODE 1 (decode):ring-3/prefetch-2. A=AD (1024), W=WdecAll, NKT=16. 3 loads/thr/stage.
//                 Wp (16 proj rows x full K, 32KB) preloaded to LDS once; wu2==0 waves
//                 add proj tile -> out[:,sidx,:].
// MODE 2 (final proj): ring-4. grid 16, B rows 2048+, each wave 16m x 64n.
// s_setprio(1) around the MFMA cluster.
// LDS: MODE 1: A 3x8K @0, B 3x16K @24576, Wp 32K @73728 (104K alloc).
//      else:   A 4x8K @0, B 4x16K @32768 (96K).
template <int MODE>
__global__ __launch_bounds__(512)
void lstm_step(const short* __restrict__ Ain, short* __restrict__ hout,
               int hstride, int hioff, int looff,
               const float* __restrict__ xnext,
               float* __restrict__ Cst,
               const short* __restrict__ W2,
               const float* __restrict__ bias,
               float* __restrict__ out, int sidx, int S) {
  constexpr int NKT  = (MODE == 0) ? 20 : 16;
  constexpr int ASTR = (MODE == 0) ? 1280 : 1024;  // A row stride == W row stride
  constexpr int RING = (MODE == 1) ? 3 : 4;
  constexpr int BOFF = (MODE == 1) ? 24576 : 32768;
  constexpr int LDSZ = (MODE == 1) ? 106496 : 98304;
  __shared__ char lds[LDSZ];
  const int tid = threadIdx.x, lane = tid & 63, wid = tid >> 6;
  const int l15 = lane & 15, l4 = lane >> 4;
  const int wm2 = wid & 3, wu2 = wid >> 2;
  const int bid = blockIdx.x;
  int m0, u0, strip;
  if (MODE == 2) {
    m0 = bid * 64; u0 = 0; strip = 0;
  } else {
    const int jb = bid >> 3;
    strip = (bid & 7) + ((jb >> 4) << 3);  // XCD-local strips
    m0 = (jb & 15) * 64;
    u0 = strip * 32;
  }
  const int wbase = wid * 1024;

  auto stage = [&](int kt, int bsel) {
    char* B = lds + BOFF + bsel * 16384;
#pragma unroll
    for (int p = 0; p < 2; ++p) {
      int idx = p * 512 + tid;
      int r = idx >> 3, jp = idx & 7;
      int j = jp ^ (r & 7);
      int gu = (MODE == 2) ? (2048 + r) : (((r >> 5) << 9) + u0 + (r & 31));
      gld_lds16(W2 + (size_t)gu * ASTR + kt * 64 + j * 8, B + p * 8192 + wbase);
    }
    char* A = lds + bsel * 8192;
    {
      int r = tid >> 3;
      int j = (tid & 7) ^ (r & 7);
      gld_lds16(Ain + (size_t)(m0 + r) * ASTR + kt * 64 + j * 8, A + wbase);
    }
  };

  // decode: preload the block's 16 proj-W rows (full K, 32KB) into LDS once.
  // slot idx=(ktw*16+row)*8+jp holds global seg j=jp^(row&7) of row (2048+strip*8+row).
  if (MODE == 1) {
    char* Wp = lds + 73728;
#pragma unroll
    for (int p = 0; p < 4; ++p) {
      int idx = p * 512 + tid;            // 0..2047
      int r2 = idx >> 3, jp = idx & 7;    // r2: ktw = r2>>4, row = r2&15
      int row = r2 & 15;
      int j = jp ^ (row & 7);
      gld_lds16(W2 + (size_t)(2048 + strip * 8 + row) * 1024 + (r2 >> 4) * 64 + j * 8,
                Wp + p * 8192 + wbase);
    }
  }

  f32x4 acc[4] = {};
  f32x4 accp = {};
  stage(0, 0);
  stage(1, 1);
  if (RING == 4) stage(2, 2);
#pragma unroll
  for (int kt = 0; kt < NKT; ++kt) {
    // block-uniform counted vmcnt: stage(kt) (and Wp on kt==0) must be complete.
    if (MODE == 1) {
      if (kt < NKT - 1) { WAITVM(3); } else { WAITVM(0); }
    } else {
      if (kt < NKT - 2) { WAITVM(6); }
      else if (kt == NKT - 2) { WAITVM(3); }
      else { WAITVM(0); }
    }
    barrier_pipe();
    if (kt + RING - 1 < NKT) stage(kt + RING - 1, (kt + RING - 1) % RING);
    const char* A = lds + (kt % RING) * 8192;
    const char* B = lds + BOFF + (kt % RING) * 16384;
    const char* Wp = lds + 73728;
    __builtin_amdgcn_s_setprio(1);
#pragma unroll
    for (int s2 = 0; s2 < 2; ++s2) {
      const int jd = s2 * 4 + l4;
      const int r = wm2 * 16 + l15;
      s16x8 av = *(const s16x8*)(A + r * 128 + ((jd ^ (r & 7)) << 4));
      if (MODE == 2) {
#pragma unroll
        for (int nt = 0; nt < 4; ++nt) {
          const int rB = wu2 * 64 + nt * 16 + l15;
          s16x8 bv = *(const s16x8*)(B + rB * 128 + ((jd ^ (rB & 7)) << 4));
          mfma16(acc[nt], av, bv);
        }
      } else {
#pragma unroll
        for (int g = 0; g < 4; ++g) {
          const int rB = g * 32 + wu2 * 16 + l15;
          s16x8 bv = *(const s16x8*)(B + rB * 128 + ((jd ^ (rB & 7)) << 4));
          mfma16(acc[g], av, bv);
        }
        if (MODE == 1 && wu2 == 0) {
          const int rp = l15;
          s16x8 bvp = *(const s16x8*)(Wp + kt * 2048 + rp * 128 + ((jd ^ (rp & 7)) << 4));
          mfma16(accp, av, bvp);
        }
      }
    }
    __builtin_amdgcn_s_setprio(0);
  }

  asm volatile("s_nop 7\ns_nop 7\ns_nop 7");

  if (MODE == 2) {
#pragma unroll
    for (int nt = 0; nt < 4; ++nt) {
      const int n = wu2 * 64 + nt * 16 + l15;
      const float bb = bias[2048 + n];
#pragma unroll
      for (int rr = 0; rr < 4; ++rr) {
        const int m = m0 + wm2 * 16 + (l4 << 2) + rr;
        out[(size_t)m * ((size_t)S * 128) + (size_t)sidx * 128 + n] = acc[nt][rr] + bb;
      }
    }
    return;
  }

  // gate epilogue
  const int u = u0 + wu2 * 16 + l15;
  const float bi = bias[u], bf_ = bias[512 + u], bg = bias[1024 + u], bo = bias[1536 + u];
#pragma unroll
  for (int rr = 0; rr < 4; ++rr) {
    const int m = m0 + wm2 * 16 + (l4 << 2) + rr;
    const size_t off = (size_t)m * 512 + u;
    float ig = sigf(acc[0][rr] + bi);
    float fg = sigf(acc[1][rr] + bf_);
    float gg = tanhf2(acc[2][rr] + bg);
    float og = sigf(acc[3][rr] + bo);
    float cn = fg * Cst[off] + ig * gg;
    Cst[off] = cn;
    float hv = og * tanhf2(cn);
    short hh, hl; split2(hv, hh, hl);
    hout[(size_t)m * hstride + hioff + u] = hh;
    hout[(size_t)m * hstride + looff + u] = hl;
  }

  // fused projection store (decode): block (mblk,strip) -> rows m0.., cols strip*8..+8
  if (MODE == 1 && wu2 == 0 && l15 < 8) {
    const int n = strip * 8 + l15;
    const float bb = bias[2048 + n];
#pragma unroll
    for (int rr = 0; rr < 4; ++rr) {
      const int m = m0 + wm2 * 16 + (l4 << 2) + rr;
      out[(size_t)m * ((size_t)S * 128) + (size_t)sidx * 128 + n] = accp[rr] + bb;
    }
  }

  // next-x conversion (warmup only; strip-0 blocks cover their 64 m rows)
  if (MODE == 0 && xnext != nullptr && strip == 0) {
    const int r = tid >> 3;
    const int c0 = (tid & 7) * 16;
    const float* src = xnext + (size_t)(m0 + r) * 16384 + c0;
    short* dst = hout + (size_t)(m0 + r) * 1280;
#pragma unroll
    for (int j = 0; j < 16; j += 8) {
      floatx4 a = *(const floatx4*)(src + j);
      floatx4 b = *(const floatx4*)(src + j + 4);
      s16x8 vh, vl;
#pragma unroll
      for (int e = 0; e < 8; ++e) {
        float x = (e < 4) ? a[e] : b[e - 4];
        short hi, lo; split2(x, hi, lo);
        vh[e] = hi; vl[e] = lo;
      }
      *(s16x8*)(dst + c0 + j) = vh;
      *(s16x8*)(dst + 640 + c0 + j) = vl;
    }
  }
}

extern "C" void kernel_launch(void* const* d_in, const int* in_sizes, int n_in,
                              void* d_out, int out_size, void* d_ws, size_t ws_size,
                              hipStream_t stream) {
  const float* inputs = (const float*)d_in[0];  // [1024,128,128]
  const float* Wk = (const float*)d_in[1];      // [128,2048]
  const float* Wr = (const float*)d_in[2];      // [512,2048]
  const float* bias = (const float*)d_in[3];    // [2048]
  const float* Wd = (const float*)d_in[4];      // [512,128]
  const float* bd = (const float*)d_in[5];      // [128]
  float* out = (float*)d_out;                   // [1024, S, 128]
  const int S = out_size / (1024 * 128);        // 96

  char* w = (char*)d_ws;
  short* WT2     = (short*)w; w += (size_t)2048 * 1280 * 2;  // 5.24 MB
  short* WdecAll = (short*)w; w += (size_t)2208 * 1024 * 2;  // 4.52 MB (rows 2176..2207 pad)
  float* bdecA   = (float*)w; w += (size_t)2176 * 4;
  short* AW0 = (short*)w; w += (size_t)1024 * 1280 * 2;      // 2.62 MB
  short* AW1 = (short*)w; w += (size_t)1024 * 1280 * 2;      // 2.62 MB
  short* AD0 = (short*)w; w += (size_t)1024 * 1024 * 2;      // 2.10 MB
  short* AD1 = (short*)w; w += (size_t)1024 * 1024 * 2;      // 2.10 MB
  float* Cst = (float*)w; w += (size_t)1024 * 512 * 4;       // 2.10 MB
  if ((size_t)(w - (char*)d_ws) > ws_size) return;           // clean fail

  hipMemsetAsync(AW0, 0, (size_t)1024 * 1280 * 2, stream);
  hipMemsetAsync(Cst, 0, (size_t)1024 * 512 * 4, stream);

  prep_w2<<<dim3(10, 32), 256, 0, stream>>>(Wk, Wr, WT2);
  wdec_split<<<dim3(8, 512), 256, 0, stream>>>(Wd, Wk, Wr, WdecAll);
  wd_append<<<256, 256, 0, stream>>>(Wd, WdecAll);
  bdec_all<<<9, 256, 0, stream>>>(bd, Wk, bias, bdecA);
  x0_init<<<64, 256, 0, stream>>>(inputs, AW0);

  short* AW[2] = { AW0, AW1 };
  short* AD[2] = { AD0, AD1 };

  // warmup: steps 0..126 -> AW ping-pong; step 127 -> AD0 ([h_hi|h_lo], stride 1024)
  for (int t = 0; t < 127; ++t) {
    lstm_step<0><<<256, 512, 0, stream>>>(
        AW[t & 1], AW[(t + 1) & 1], 1280, 128, 768,
        inputs + (size_t)(t + 1) * 128, Cst, WT2, bias, nullptr, 0, S);
  }
  lstm_step<0><<<256, 512, 0, stream>>>(
      AW[1], AD[0], 1024, 0, 512, nullptr, Cst, WT2, bias, nullptr, 0, S);

  // decode: step s computes h_s (gates) and out[:,s-1,:] (fused proj of h_{s-1})
  for (int s = 1; s < S; ++s) {
    lstm_step<1><<<256, 512, 0, stream>>>(
        AD[(s + 1) & 1], AD[s & 1], 1024, 0, 512, nullptr, Cst,
        WdecAll, bdecA, out, s - 1, S);
  }
  // final projection of h_{S-1}
  lstm_step<2><<<16, 512, 0, stream>>>(
      AD[(S - 1) & 1], nullptr, 0, 0, 0, nullptr, Cst,
      WdecAll, bdecA, out, S - 1, S);
}